// Round 4
// baseline (407.323 us; speedup 1.0000x reference)
//
#include <hip/hip_runtime.h>

#define PI_F 3.14159265358979323846f

typedef float v4f __attribute__((ext_vector_type(4)));

// ---------------- workspace layout (float offsets) ----------------
#define WS_SPEC   0u          // 32*128*1024  [b][t][k]
#define WS_H0     4194304u    // 32*32*128    [b][o][t]
#define WS_ACC    4325376u    // 32*128*32    [b][t][o]
#define WS_V      4456448u    // 32*32*128    [b][c][t]
#define WS_WTIN   4587520u    // 1024*32      [k][o]
#define WS_WST    4620288u    // 32*256       [m][o2]
#define WS_WDT    4628480u    // 256*32       [o2][c]
#define WS_FRAMES 4636672u    // 32*32*2048   [c][f][j]
#define WS_RES    6733824u    // 32*32768     [c][s]
// total 7782400 floats = ~29.7 MB

// ---- 2048-pt complex DIT FFT, input already in bit-reversed order, 256 thr ----
__device__ __forceinline__ void fft2048_stages(float2* buf, int tid) {
  for (int stage = 0; stage < 11; ++stage) {
    int half = 1 << stage;
    float base = -PI_F / (float)half;   // -2*pi/len
    for (int t = tid; t < 1024; t += 256) {
      int j  = t & (half - 1);
      int i0 = ((t >> stage) << (stage + 1)) + j;
      int i1 = i0 + half;
      float s, c;
      __sincosf(base * (float)j, &s, &c);   // e^{-i*2pi*j/len} = c + i*s
      float2 u = buf[i0];
      float2 w = buf[i1];
      float tr = c * w.x - s * w.y;
      float ti = c * w.y + s * w.x;
      buf[i0] = make_float2(u.x + tr, u.y + ti);
      buf[i1] = make_float2(u.x - tr, u.y - ti);
    }
    __syncthreads();
  }
}

// ---------------- STFT: |rfft(frame*hann)|/sqrt(2048), keep k<1024 ----------------
__global__ __launch_bounds__(256) void k_stft(const float* __restrict__ audio,
                                              float* __restrict__ spec) {
  __shared__ float2 buf[2048];
  int b = blockIdx.x >> 7;
  int f = blockIdx.x & 127;
  for (int j = threadIdx.x; j < 2048; j += 256) {
    int idx = f * 256 + j;
    float v = (idx < 32768) ? audio[b * 32768 + idx] : 0.f;
    float h = 0.5f - 0.5f * __cosf(0.0030679615757712823f * (float)j); // 2pi/2048
    buf[__brev((unsigned)j) >> 21] = make_float2(v * h, 0.f);
  }
  __syncthreads();
  fft2048_stages(buf, threadIdx.x);
  const float scale = 0.022097086912079608f;  // 1/sqrt(2048)
  for (int k = threadIdx.x; k < 1024; k += 256) {
    float2 X = buf[k];
    spec[(b * 128 + f) * 1024 + k] = sqrtf(X.x * X.x + X.y * X.y) * scale;
  }
}

// ---------------- weight transposes ----------------
__global__ __launch_bounds__(256) void k_prep(const float* __restrict__ Win,
                                              const float* __restrict__ Ws,
                                              const float* __restrict__ Wd,
                                              float* __restrict__ WT,
                                              float* __restrict__ WsT,
                                              float* __restrict__ WdT) {
  int i = blockIdx.x * 256 + threadIdx.x;
  if (i < 32768) { int o = i >> 10, k = i & 1023; WT[k * 32 + o] = Win[i]; }
  if (i < 8192)  { int o2 = i >> 5, m = i & 31;   WsT[m * 256 + o2] = Ws[i]; }
  if (i < 8192)  { int c = i >> 8, o2 = i & 255;  WdT[o2 * 32 + c] = Wd[i]; }
}

// ---------------- proj_in: h0[b,o,t] = sum_k WT[k][o]*spec[b,t,k] + bias ----------------
__global__ __launch_bounds__(256) void k_proj_in(const float* __restrict__ spec,
                                                 const float* __restrict__ WT,
                                                 const float* __restrict__ bias,
                                                 float* __restrict__ h0) {
  __shared__ float specL[8][1024];
  __shared__ float red[32][8][8];   // [o][tt][p]
  int b  = blockIdx.x >> 4;
  int t0 = (blockIdx.x & 15) * 8;
  for (int i = threadIdx.x; i < 8192; i += 256) {
    int tt = i >> 10, k = i & 1023;
    specL[tt][k] = spec[(b * 128 + t0 + tt) * 1024 + k];
  }
  __syncthreads();
  int o = threadIdx.x & 31, p = threadIdx.x >> 5;
  float part[8] = {0.f,0.f,0.f,0.f,0.f,0.f,0.f,0.f};
  for (int i = 0; i < 128; ++i) {
    int k = p * 128 + ((i + p * 4) & 127);   // stagger: conflict-free banks across p
    float w = WT[k * 32 + o];
#pragma unroll
    for (int tt = 0; tt < 8; ++tt) part[tt] += w * specL[tt][k];
  }
#pragma unroll
  for (int tt = 0; tt < 8; ++tt) red[o][tt][p] = part[tt];
  __syncthreads();
  int oo = threadIdx.x >> 3, tt2 = threadIdx.x & 7;
  float s = bias[oo];
#pragma unroll
  for (int p2 = 0; p2 < 8; ++p2) s += red[oo][tt2][p2];
  h0[b * 4096 + oo * 128 + t0 + tt2] = s;
}

// ---------------- 8-block anticausal chain, one WG per batch ----------------
__global__ __launch_bounds__(1024) void k_chain(const float* __restrict__ h0,
                                                const float* __restrict__ bw,
                                                const float* __restrict__ bb,
                                                float* __restrict__ accout) {
  __shared__ float hL[32][128];
  __shared__ float w0L[32][32], w1L[32][32];
  __shared__ float bL[32];
  __shared__ float red[16];
  __shared__ float normL;
  int b = blockIdx.x;
  int tid = threadIdx.x;
  int t = tid & 127, og = tid >> 7;   // og 0..7
  for (int i = tid; i < 4096; i += 1024) hL[i >> 7][i & 127] = h0[b * 4096 + i];
  float acc[4] = {0.f, 0.f, 0.f, 0.f};
  const int DIL[8] = {1, 2, 4, 8, 16, 32, 64, 1};
  for (int blk = 0; blk < 8; ++blk) {
    __syncthreads();
    {
      int o = tid >> 5, m = tid & 31;   // tid < 1024 covers all 32x32
      w0L[o][m] = bw[((blk * 32 + o) * 32 + m) * 2 + 0];
      w1L[o][m] = bw[((blk * 32 + o) * 32 + m) * 2 + 1];
      if (tid < 32) bL[tid] = bb[blk * 32 + tid];
    }
    __syncthreads();
    int d = DIL[blk];
    int t2 = t + d;
    int t2c = (t2 < 128) ? t2 : 0;
    float fm = (t2 < 128) ? 1.f : 0.f;
    float y[4];
#pragma unroll
    for (int n = 0; n < 4; ++n) y[n] = bL[og * 4 + n];
    for (int m = 0; m < 32; ++m) {
      float hv = hL[m][t];
      float hf = hL[m][t2c] * fm;
#pragma unroll
      for (int n = 0; n < 4; ++n)
        y[n] += w0L[og * 4 + n][m] * hv + w1L[og * 4 + n][m] * hf;
    }
    float lmax = 0.f;
#pragma unroll
    for (int n = 0; n < 4; ++n) {
      float s = y[n];
      s = (s > 0.f) ? s : 0.2f * s;     // leaky_relu 0.2
      s += hL[og * 4 + n][t];           // residual
      y[n] = s;
      lmax = fmaxf(lmax, fabsf(s));
    }
    for (int off = 32; off > 0; off >>= 1)
      lmax = fmaxf(lmax, __shfl_down(lmax, off, 64));
    if ((tid & 63) == 0) red[tid >> 6] = lmax;
    __syncthreads();
    if (tid == 0) {
      float m = 0.f;
      for (int i2 = 0; i2 < 16; ++i2) m = fmaxf(m, red[i2]);
      normL = 1.f / (m + 1e-8f);
    }
    __syncthreads();
    float nm = normL;
#pragma unroll
    for (int n = 0; n < 4; ++n) {
      float hv = y[n] * nm;
      hL[og * 4 + n][t] = hv;
      acc[n] += hv;
    }
  }
#pragma unroll
  for (int n = 0; n < 4; ++n)
    accout[b * 4096 + t * 32 + og * 4 + n] = acc[n];
}

// ---------------- sparse (relu proj 32->256, to d_out) + dense (256->32, to ws) ----------------
__global__ __launch_bounds__(256) void k_sparse_dense(const float* __restrict__ acc,
                                                      const float* __restrict__ WsT,
                                                      const float* __restrict__ bs,
                                                      const float* __restrict__ WdT,
                                                      const float* __restrict__ bd,
                                                      float* __restrict__ out_sparse,
                                                      float* __restrict__ v) {
  __shared__ float accL[32];
  __shared__ float sL[256];
  __shared__ float red[8][32];
  int b = blockIdx.x >> 7, t = blockIdx.x & 127;
  int tid = threadIdx.x;
  if (tid < 32) accL[tid] = acc[b * 4096 + t * 32 + tid];
  __syncthreads();
  float s = bs[tid];
  for (int m = 0; m < 32; ++m) s += WsT[m * 256 + tid] * accL[m];
  s = fmaxf(s, 0.f);
  out_sparse[b * 32768 + tid * 128 + t] = s;
  sL[tid] = s;
  __syncthreads();
  int c = tid & 31, p = tid >> 5;
  float part = 0.f;
  for (int j = 0; j < 32; ++j) {
    int o2 = p * 32 + j;
    part += WdT[o2 * 32 + c] * sL[o2];
  }
  red[p][c] = part;
  __syncthreads();
  if (tid < 32) {
    float vv = bd[tid];
    for (int p2 = 0; p2 < 8; ++p2) vv += red[p2][tid];
    v[b * 4096 + tid * 128 + t] = vv;
  }
}

// ---------------- resonance frames: irfft_2048(c^(f+1)) * hann, f<32 only ----------------
__global__ __launch_bounds__(256) void k_res_frames(const float* __restrict__ resin,
                                                    float* __restrict__ frames) {
  __shared__ float2 buf[2048];
  int c = blockIdx.x >> 5;
  int f = blockIdx.x & 31;
  float e = (float)(f + 1);
  for (int k = threadIdx.x; k < 2048; k += 256) {
    int kk = (k <= 1024) ? k : 2048 - k;   // Hermitian (real) extension
    float cv = resin[c * 1025 + kk];
    cv = fminf(fmaxf(cv, 0.f), 0.9999f);
    float m = __powf(cv, e);
    buf[__brev((unsigned)k) >> 21] = make_float2(m, 0.f);
  }
  __syncthreads();
  fft2048_stages(buf, threadIdx.x);
  for (int j = threadIdx.x; j < 2048; j += 256) {
    float h = 0.5f - 0.5f * __cosf(0.0030679615757712823f * (float)j);
    frames[(c * 32 + f) * 2048 + j] = buf[j].x * (1.f / 2048.f) * h;
  }
}

// ---------------- overlap-add (hop 1024): at most 2 frames per sample ----------------
__global__ __launch_bounds__(256) void k_res_assemble(const float* __restrict__ frames,
                                                      float* __restrict__ res) {
  int i = blockIdx.x * 256 + threadIdx.x;   // 0 .. 32*32768
  int c = i >> 15, s = i & 32767;
  int g = s >> 10, j0 = s & 1023;
  float v = frames[(c * 32 + g) * 2048 + j0];
  if (g > 0) v += frames[(c * 32 + g - 1) * 2048 + j0 + 1024];
  res[i] = v;
}

// ---------------- final conv: y[b,256q+r] += sum_c sum_u v[b,c,q-u]*res[c,256u+r] ----------------
// Wave-level tasks: each of the block's 4 waves takes one (qt, uc<=qt, c-half)
// task for the block's batch b -> 2304 identical tasks, perfectly balanced.
// Lane owns 4 consecutive r (float4): res loads are coalesced b128, inner FMAs
// are float4 ops -> v_pk_fma_f32 (2 fp32/lane/cyc). Static 31-float window from
// zero-padded LDS v rows (wave-uniform b128 broadcast reads, wbase 16-aligned).
#define VROW 176   // 31 zeros | 128 v | 17 zeros  (stride 176 floats, 16B-aligned)
__global__ __launch_bounds__(256) void k_conv(const float* __restrict__ v,
                                              const float* __restrict__ res,
                                              float* __restrict__ y) {
  __shared__ __align__(16) float vLp[32 * VROW];
  int blk = blockIdx.x;            // 576 blocks = 32 b * 18
  int b = blk / 18;
  int tloc = (blk - b * 18) * 4 + (threadIdx.x >> 6);   // wave task id, 0..71
  int ch = tloc & 1;
  int p  = tloc >> 1;              // 0..35 triangular pair index
  int qt = (int)((sqrtf(8.f * (float)p + 1.f) - 1.f) * 0.5f + 1e-4f);
  int uc = p - ((qt * (qt + 1)) >> 1);
  int q0 = qt * 16, u0 = uc * 16, c0 = ch * 16;
  int lane = threadIdx.x & 63;     // r = 4*lane .. 4*lane+3

  // zero pads + stage all 32 v rows (shared by the 4 waves, same b)
  for (int i = threadIdx.x; i < 32 * VROW; i += 256) vLp[i] = 0.f;
  __syncthreads();
  for (int i = threadIdx.x; i < 4096; i += 256) {
    int c2 = i >> 7, t = i & 127;
    vLp[c2 * VROW + 31 + t] = v[b * 4096 + i];
  }
  __syncthreads();

  v4f acc[16];
#pragma unroll
  for (int qi = 0; qi < 16; ++qi) acc[qi] = (v4f)0.f;

  int wbase = q0 - u0 + 16;        // padded window start, multiple of 16
  const v4f* rres = (const v4f*)res;   // float4 index: c*8192 + u*64 + lane

  for (int c2 = 0; c2 < 16; ++c2) {
    int cc = c0 + c2;
    const float4* wrow = (const float4*)&vLp[cc * VROW + wbase];
    float w[32];
#pragma unroll
    for (int i = 0; i < 8; ++i) {
      float4 t4 = wrow[i];
      w[4 * i + 0] = t4.x; w[4 * i + 1] = t4.y; w[4 * i + 2] = t4.z; w[4 * i + 3] = t4.w;
    }
    const v4f* rr = rres + cc * 8192 + u0 * 64 + lane;
    v4f rv[8];
    // u-half 0: u = u0+k, k in [0,8) ;  v[q0+qi-(u0+k)] = w[15-k+qi]
#pragma unroll
    for (int k = 0; k < 8; ++k) rv[k] = rr[k * 64];
#pragma unroll
    for (int k = 0; k < 8; ++k)
#pragma unroll
      for (int qi = 0; qi < 16; ++qi) acc[qi] += rv[k] * w[15 - k + qi];
    // u-half 1: u = u0+8+k -> w[7-k+qi]
#pragma unroll
    for (int k = 0; k < 8; ++k) rv[k] = rr[(k + 8) * 64];
#pragma unroll
    for (int k = 0; k < 8; ++k)
#pragma unroll
      for (int qi = 0; qi < 16; ++qi) acc[qi] += rv[k] * w[7 - k + qi];
  }

  float* yb = y + b * 32768 + q0 * 256 + lane * 4;
#pragma unroll
  for (int qi = 0; qi < 16; ++qi) {
    atomicAdd(yb + qi * 256 + 0, acc[qi].x);
    atomicAdd(yb + qi * 256 + 1, acc[qi].y);
    atomicAdd(yb + qi * 256 + 2, acc[qi].z);
    atomicAdd(yb + qi * 256 + 3, acc[qi].w);
  }
}

extern "C" void kernel_launch(void* const* d_in, const int* in_sizes, int n_in,
                              void* d_out, int out_size, void* d_ws, size_t ws_size,
                              hipStream_t stream) {
  const float* audio = (const float*)d_in[0];
  const float* Win   = (const float*)d_in[1];
  const float* bin   = (const float*)d_in[2];
  const float* bw    = (const float*)d_in[3];
  const float* bb    = (const float*)d_in[4];
  const float* Ws    = (const float*)d_in[5];
  const float* bs    = (const float*)d_in[6];
  const float* Wd    = (const float*)d_in[7];
  const float* bd    = (const float*)d_in[8];
  const float* reson = (const float*)d_in[9];

  float* out = (float*)d_out;           // [0,1048576) = y ; [1048576,2097152) = sparse
  float* ws  = (float*)d_ws;

  float* spec   = ws + WS_SPEC;
  float* h0     = ws + WS_H0;
  float* accb   = ws + WS_ACC;
  float* vbuf   = ws + WS_V;
  float* WT     = ws + WS_WTIN;
  float* WsT    = ws + WS_WST;
  float* WdT    = ws + WS_WDT;
  float* frames = ws + WS_FRAMES;
  float* resbuf = ws + WS_RES;

  // zero y region (atomicAdd target); d_out is poisoned before every launch
  hipMemsetAsync(d_out, 0, 1048576u * sizeof(float), stream);

  k_prep<<<128, 256, 0, stream>>>(Win, Ws, Wd, WT, WsT, WdT);
  k_res_frames<<<1024, 256, 0, stream>>>(reson, frames);
  k_res_assemble<<<4096, 256, 0, stream>>>(frames, resbuf);
  k_stft<<<4096, 256, 0, stream>>>(audio, spec);
  k_proj_in<<<512, 256, 0, stream>>>(spec, WT, bin, h0);
  k_chain<<<32, 1024, 0, stream>>>(h0, bw, bb, accb);
  k_sparse_dense<<<4096, 256, 0, stream>>>(accb, WsT, bs, WdT, bd, out + 1048576, vbuf);
  k_conv<<<576, 256, 0, stream>>>(vbuf, resbuf, out);
}

// Round 5
// 286.257 us; speedup vs baseline: 1.4229x; 1.4229x over previous
//
#include <hip/hip_runtime.h>

#define PI_F 3.14159265358979323846f

typedef float v4f __attribute__((ext_vector_type(4)));

// ---------------- workspace layout (float offsets) ----------------
#define WS_SPEC   0u          // 32*128*1024  [b][t][k]
#define WS_H0     4194304u    // 32*32*128    [b][o][t]
#define WS_ACC    4325376u    // 32*128*32    [b][t][o]
#define WS_V      4456448u    // 32*32*128    [b][c][t]
#define WS_WTIN   4587520u    // 1024*32      [k][o]
#define WS_WST    4620288u    // 32*256       [m][o2]
#define WS_WDT    4628480u    // 256*32       [o2][c]
#define WS_FRAMES 4636672u    // 32*32*2048   [c][f][j]
#define WS_RES    6733824u    // 32*32768     [c][s]
// total 7782400 floats = ~29.7 MB

// ---- 2048-pt complex DIT FFT, input already in bit-reversed order, 256 thr ----
__device__ __forceinline__ void fft2048_stages(float2* buf, int tid) {
  for (int stage = 0; stage < 11; ++stage) {
    int half = 1 << stage;
    float base = -PI_F / (float)half;   // -2*pi/len
    for (int t = tid; t < 1024; t += 256) {
      int j  = t & (half - 1);
      int i0 = ((t >> stage) << (stage + 1)) + j;
      int i1 = i0 + half;
      float s, c;
      __sincosf(base * (float)j, &s, &c);   // e^{-i*2pi/len*j} = c + i*s
      float2 u = buf[i0];
      float2 w = buf[i1];
      float tr = c * w.x - s * w.y;
      float ti = c * w.y + s * w.x;
      buf[i0] = make_float2(u.x + tr, u.y + ti);
      buf[i1] = make_float2(u.x - tr, u.y - ti);
    }
    __syncthreads();
  }
}

// ---------------- STFT: |rfft(frame*hann)|/sqrt(2048), keep k<1024 ----------------
__global__ __launch_bounds__(256) void k_stft(const float* __restrict__ audio,
                                              float* __restrict__ spec) {
  __shared__ float2 buf[2048];
  int b = blockIdx.x >> 7;
  int f = blockIdx.x & 127;
  for (int j = threadIdx.x; j < 2048; j += 256) {
    int idx = f * 256 + j;
    float v = (idx < 32768) ? audio[b * 32768 + idx] : 0.f;
    float h = 0.5f - 0.5f * __cosf(0.0030679615757712823f * (float)j); // 2pi/2048
    buf[__brev((unsigned)j) >> 21] = make_float2(v * h, 0.f);
  }
  __syncthreads();
  fft2048_stages(buf, threadIdx.x);
  const float scale = 0.022097086912079608f;  // 1/sqrt(2048)
  for (int k = threadIdx.x; k < 1024; k += 256) {
    float2 X = buf[k];
    spec[(b * 128 + f) * 1024 + k] = sqrtf(X.x * X.x + X.y * X.y) * scale;
  }
}

// ---------------- weight transposes ----------------
__global__ __launch_bounds__(256) void k_prep(const float* __restrict__ Win,
                                              const float* __restrict__ Ws,
                                              const float* __restrict__ Wd,
                                              float* __restrict__ WT,
                                              float* __restrict__ WsT,
                                              float* __restrict__ WdT) {
  int i = blockIdx.x * 256 + threadIdx.x;
  if (i < 32768) { int o = i >> 10, k = i & 1023; WT[k * 32 + o] = Win[i]; }
  if (i < 8192)  { int o2 = i >> 5, m = i & 31;   WsT[m * 256 + o2] = Ws[i]; }
  if (i < 8192)  { int c = i >> 8, o2 = i & 255;  WdT[o2 * 32 + c] = Wd[i]; }
}

// ---------------- proj_in: h0[b,o,t] = sum_k WT[k][o]*spec[b,t,k] + bias ----------------
__global__ __launch_bounds__(256) void k_proj_in(const float* __restrict__ spec,
                                                 const float* __restrict__ WT,
                                                 const float* __restrict__ bias,
                                                 float* __restrict__ h0) {
  __shared__ float specL[8][1024];
  __shared__ float red[32][8][8];   // [o][tt][p]
  int b  = blockIdx.x >> 4;
  int t0 = (blockIdx.x & 15) * 8;
  for (int i = threadIdx.x; i < 8192; i += 256) {
    int tt = i >> 10, k = i & 1023;
    specL[tt][k] = spec[(b * 128 + t0 + tt) * 1024 + k];
  }
  __syncthreads();
  int o = threadIdx.x & 31, p = threadIdx.x >> 5;
  float part[8] = {0.f,0.f,0.f,0.f,0.f,0.f,0.f,0.f};
  for (int i = 0; i < 128; ++i) {
    int k = p * 128 + ((i + p * 4) & 127);   // stagger: conflict-free banks across p
    float w = WT[k * 32 + o];
#pragma unroll
    for (int tt = 0; tt < 8; ++tt) part[tt] += w * specL[tt][k];
  }
#pragma unroll
  for (int tt = 0; tt < 8; ++tt) red[o][tt][p] = part[tt];
  __syncthreads();
  int oo = threadIdx.x >> 3, tt2 = threadIdx.x & 7;
  float s = bias[oo];
#pragma unroll
  for (int p2 = 0; p2 < 8; ++p2) s += red[oo][tt2][p2];
  h0[b * 4096 + oo * 128 + t0 + tt2] = s;
}

// ---------------- 8-block anticausal chain, one WG per batch ----------------
__global__ __launch_bounds__(1024) void k_chain(const float* __restrict__ h0,
                                                const float* __restrict__ bw,
                                                const float* __restrict__ bb,
                                                float* __restrict__ accout) {
  __shared__ float hL[32][128];
  __shared__ float w0L[32][32], w1L[32][32];
  __shared__ float bL[32];
  __shared__ float red[16];
  __shared__ float normL;
  int b = blockIdx.x;
  int tid = threadIdx.x;
  int t = tid & 127, og = tid >> 7;   // og 0..7
  for (int i = tid; i < 4096; i += 1024) hL[i >> 7][i & 127] = h0[b * 4096 + i];
  float acc[4] = {0.f, 0.f, 0.f, 0.f};
  const int DIL[8] = {1, 2, 4, 8, 16, 32, 64, 1};
  for (int blk = 0; blk < 8; ++blk) {
    __syncthreads();
    {
      int o = tid >> 5, m = tid & 31;   // tid < 1024 covers all 32x32
      w0L[o][m] = bw[((blk * 32 + o) * 32 + m) * 2 + 0];
      w1L[o][m] = bw[((blk * 32 + o) * 32 + m) * 2 + 1];
      if (tid < 32) bL[tid] = bb[blk * 32 + tid];
    }
    __syncthreads();
    int d = DIL[blk];
    int t2 = t + d;
    int t2c = (t2 < 128) ? t2 : 0;
    float fm = (t2 < 128) ? 1.f : 0.f;
    float y[4];
#pragma unroll
    for (int n = 0; n < 4; ++n) y[n] = bL[og * 4 + n];
    for (int m = 0; m < 32; ++m) {
      float hv = hL[m][t];
      float hf = hL[m][t2c] * fm;
#pragma unroll
      for (int n = 0; n < 4; ++n)
        y[n] += w0L[og * 4 + n][m] * hv + w1L[og * 4 + n][m] * hf;
    }
    float lmax = 0.f;
#pragma unroll
    for (int n = 0; n < 4; ++n) {
      float s = y[n];
      s = (s > 0.f) ? s : 0.2f * s;     // leaky_relu 0.2
      s += hL[og * 4 + n][t];           // residual
      y[n] = s;
      lmax = fmaxf(lmax, fabsf(s));
    }
    for (int off = 32; off > 0; off >>= 1)
      lmax = fmaxf(lmax, __shfl_down(lmax, off, 64));
    if ((tid & 63) == 0) red[tid >> 6] = lmax;
    __syncthreads();
    if (tid == 0) {
      float m = 0.f;
      for (int i2 = 0; i2 < 16; ++i2) m = fmaxf(m, red[i2]);
      normL = 1.f / (m + 1e-8f);
    }
    __syncthreads();
    float nm = normL;
#pragma unroll
    for (int n = 0; n < 4; ++n) {
      float hv = y[n] * nm;
      hL[og * 4 + n][t] = hv;
      acc[n] += hv;
    }
  }
#pragma unroll
  for (int n = 0; n < 4; ++n)
    accout[b * 4096 + t * 32 + og * 4 + n] = acc[n];
}

// ---------------- sparse (relu proj 32->256, to d_out) + dense (256->32, to ws) ----------------
__global__ __launch_bounds__(256) void k_sparse_dense(const float* __restrict__ acc,
                                                      const float* __restrict__ WsT,
                                                      const float* __restrict__ bs,
                                                      const float* __restrict__ WdT,
                                                      const float* __restrict__ bd,
                                                      float* __restrict__ out_sparse,
                                                      float* __restrict__ v) {
  __shared__ float accL[32];
  __shared__ float sL[256];
  __shared__ float red[8][32];
  int b = blockIdx.x >> 7, t = blockIdx.x & 127;
  int tid = threadIdx.x;
  if (tid < 32) accL[tid] = acc[b * 4096 + t * 32 + tid];
  __syncthreads();
  float s = bs[tid];
  for (int m = 0; m < 32; ++m) s += WsT[m * 256 + tid] * accL[m];
  s = fmaxf(s, 0.f);
  out_sparse[b * 32768 + tid * 128 + t] = s;
  sL[tid] = s;
  __syncthreads();
  int c = tid & 31, p = tid >> 5;
  float part = 0.f;
  for (int j = 0; j < 32; ++j) {
    int o2 = p * 32 + j;
    part += WdT[o2 * 32 + c] * sL[o2];
  }
  red[p][c] = part;
  __syncthreads();
  if (tid < 32) {
    float vv = bd[tid];
    for (int p2 = 0; p2 < 8; ++p2) vv += red[p2][tid];
    v[b * 4096 + tid * 128 + t] = vv;
  }
}

// ---------------- resonance frames: irfft_2048(c^(f+1)) * hann, f<32 only ----------------
__global__ __launch_bounds__(256) void k_res_frames(const float* __restrict__ resin,
                                                    float* __restrict__ frames) {
  __shared__ float2 buf[2048];
  int c = blockIdx.x >> 5;
  int f = blockIdx.x & 31;
  float e = (float)(f + 1);
  for (int k = threadIdx.x; k < 2048; k += 256) {
    int kk = (k <= 1024) ? k : 2048 - k;   // Hermitian (real) extension
    float cv = resin[c * 1025 + kk];
    cv = fminf(fmaxf(cv, 0.f), 0.9999f);
    float m = __powf(cv, e);
    buf[__brev((unsigned)k) >> 21] = make_float2(m, 0.f);
  }
  __syncthreads();
  fft2048_stages(buf, threadIdx.x);
  for (int j = threadIdx.x; j < 2048; j += 256) {
    float h = 0.5f - 0.5f * __cosf(0.0030679615757712823f * (float)j);
    frames[(c * 32 + f) * 2048 + j] = buf[j].x * (1.f / 2048.f) * h;
  }
}

// ---------------- overlap-add (hop 1024): at most 2 frames per sample ----------------
__global__ __launch_bounds__(256) void k_res_assemble(const float* __restrict__ frames,
                                                      float* __restrict__ res) {
  int i = blockIdx.x * 256 + threadIdx.x;   // 0 .. 32*32768
  int c = i >> 15, s = i & 32767;
  int g = s >> 10, j0 = s & 1023;
  float v = frames[(c * 32 + g) * 2048 + j0];
  if (g > 0) v += frames[(c * 32 + g - 1) * 2048 + j0 + 1024];
  res[i] = v;
}

// ---------------- final conv: y[b,256q+r] += sum_c sum_u v[b,c,q-u]*res[c,256u+r] ----------------
// Block = (b, one (qt,uc<=qt) pair). All 4 waves share the SAME output tile;
// wave w handles channels 8w..8w+7. Lane owns an r-quad (v4f) -> coalesced b128
// res loads + v_pk_fma_f32 core. The 4 waves' accumulators are reduced in LDS
// (4 short phases), then ONE cooperative atomic pass with thread i covering
// dwords i, i+256, ... -> each atomic wave-instruction spans 64 CONSECUTIVE
// dwords = 4 fully-covered 64B lines (round-3's 16B-stride atomics caused 4x
// HBM writeback amplification, WRITE_SIZE 147MB -> that was the regression).
#define VROW 176   // 31 zeros | 128 v | 17 zeros  (stride 176 floats, 16B-aligned)
__global__ __launch_bounds__(256) void k_conv(const float* __restrict__ v,
                                              const float* __restrict__ res,
                                              float* __restrict__ y) {
  __shared__ __align__(16) float vLp[32 * VROW];   // 22528 B
  __shared__ __align__(16) float yL[4096];         // 16384 B
  int blk = blockIdx.x;            // 1152 = 32 b * 36 pairs
  int b = blk / 36;
  int p = blk - b * 36;
  int qt = (int)((sqrtf(8.f * (float)p + 1.f) - 1.f) * 0.5f + 1e-4f);
  int uc = p - ((qt * (qt + 1)) >> 1);
  int q0 = qt * 16, u0 = uc * 16;
  int wave = threadIdx.x >> 6;
  int lane = threadIdx.x & 63;     // r = 4*lane .. 4*lane+3
  int c0 = wave * 8;

  // zero pads + stage all 32 v rows (shared: all waves same b)
  for (int i = threadIdx.x; i < 32 * VROW; i += 256) vLp[i] = 0.f;
  __syncthreads();
  for (int i = threadIdx.x; i < 4096; i += 256) {
    int c2 = i >> 7, t = i & 127;
    vLp[c2 * VROW + 31 + t] = v[b * 4096 + i];
  }
  __syncthreads();

  v4f acc[16];
#pragma unroll
  for (int qi = 0; qi < 16; ++qi) acc[qi] = (v4f)0.f;

  int wbase = q0 - u0 + 16;        // padded window start, multiple of 16
  const v4f* rres = (const v4f*)res;   // float4 index: c*8192 + u*64 + lane

  for (int c2 = 0; c2 < 8; ++c2) {
    int cc = c0 + c2;
    const float4* wrow = (const float4*)&vLp[cc * VROW + wbase];
    float w[32];
#pragma unroll
    for (int i = 0; i < 8; ++i) {
      float4 t4 = wrow[i];
      w[4 * i + 0] = t4.x; w[4 * i + 1] = t4.y; w[4 * i + 2] = t4.z; w[4 * i + 3] = t4.w;
    }
    const v4f* rr = rres + cc * 8192 + u0 * 64 + lane;
    v4f rv[8];
    // u-half 0: u = u0+k, k in [0,8) ;  v[q0+qi-(u0+k)] = w[15-k+qi]
#pragma unroll
    for (int k = 0; k < 8; ++k) rv[k] = rr[k * 64];
#pragma unroll
    for (int k = 0; k < 8; ++k)
#pragma unroll
      for (int qi = 0; qi < 16; ++qi) acc[qi] += rv[k] * w[15 - k + qi];
    // u-half 1: u = u0+8+k -> w[7-k+qi]
#pragma unroll
    for (int k = 0; k < 8; ++k) rv[k] = rr[(k + 8) * 64];
#pragma unroll
    for (int k = 0; k < 8; ++k)
#pragma unroll
      for (int qi = 0; qi < 16; ++qi) acc[qi] += rv[k] * w[7 - k + qi];
  }

  // cross-wave reduce in LDS: wave 0 stores, waves 1..3 add in turn
  v4f* yv = (v4f*)yL;              // index qi*64 + lane
  for (int w = 0; w < 4; ++w) {
    __syncthreads();
    if (wave == w) {
      if (w == 0) {
#pragma unroll
        for (int qi = 0; qi < 16; ++qi) yv[qi * 64 + lane] = acc[qi];
      } else {
#pragma unroll
        for (int qi = 0; qi < 16; ++qi) {
          v4f t = yv[qi * 64 + lane];
          yv[qi * 64 + lane] = t + acc[qi];
        }
      }
    }
  }
  __syncthreads();

  // one coalesced atomic pass: 64 consecutive dwords per wave-instruction
  float* yb = y + b * 32768 + q0 * 256;
  for (int i = threadIdx.x; i < 4096; i += 256)
    atomicAdd(yb + i, yL[i]);
}

extern "C" void kernel_launch(void* const* d_in, const int* in_sizes, int n_in,
                              void* d_out, int out_size, void* d_ws, size_t ws_size,
                              hipStream_t stream) {
  const float* audio = (const float*)d_in[0];
  const float* Win   = (const float*)d_in[1];
  const float* bin   = (const float*)d_in[2];
  const float* bw    = (const float*)d_in[3];
  const float* bb    = (const float*)d_in[4];
  const float* Ws    = (const float*)d_in[5];
  const float* bs    = (const float*)d_in[6];
  const float* Wd    = (const float*)d_in[7];
  const float* bd    = (const float*)d_in[8];
  const float* reson = (const float*)d_in[9];

  float* out = (float*)d_out;           // [0,1048576) = y ; [1048576,2097152) = sparse
  float* ws  = (float*)d_ws;

  float* spec   = ws + WS_SPEC;
  float* h0     = ws + WS_H0;
  float* accb   = ws + WS_ACC;
  float* vbuf   = ws + WS_V;
  float* WT     = ws + WS_WTIN;
  float* WsT    = ws + WS_WST;
  float* WdT    = ws + WS_WDT;
  float* frames = ws + WS_FRAMES;
  float* resbuf = ws + WS_RES;

  // zero y region (atomicAdd target); d_out is poisoned before every launch
  hipMemsetAsync(d_out, 0, 1048576u * sizeof(float), stream);

  k_prep<<<128, 256, 0, stream>>>(Win, Ws, Wd, WT, WsT, WdT);
  k_res_frames<<<1024, 256, 0, stream>>>(reson, frames);
  k_res_assemble<<<4096, 256, 0, stream>>>(frames, resbuf);
  k_stft<<<4096, 256, 0, stream>>>(audio, spec);
  k_proj_in<<<512, 256, 0, stream>>>(spec, WT, bin, h0);
  k_chain<<<32, 1024, 0, stream>>>(h0, bw, bb, accb);
  k_sparse_dense<<<4096, 256, 0, stream>>>(accb, WsT, bs, WdT, bd, out + 1048576, vbuf);
  k_conv<<<1152, 256, 0, stream>>>(vbuf, resbuf, out);
}

// Round 6
// 254.106 us; speedup vs baseline: 1.6030x; 1.1265x over previous
//
#include <hip/hip_runtime.h>

#define PI_F 3.14159265358979323846f

typedef float v2f __attribute__((ext_vector_type(2)));
typedef float v4f __attribute__((ext_vector_type(4)));

// v_pk_fma_f32: D = S0*S1 + S2 (packed 2xf32). op_sel broadcasts of S1:
//   LO: both result halves use lo(S1);  HI: both use hi(S1).
#define PK_FMA_LO(d, a, wpair) \
  asm("v_pk_fma_f32 %0, %1, %2, %0 op_sel:[0,0,0] op_sel_hi:[1,0,1]" \
      : "+v"(d) : "v"(a), "v"(wpair))
#define PK_FMA_HI(d, a, wpair) \
  asm("v_pk_fma_f32 %0, %1, %2, %0 op_sel:[0,1,0] op_sel_hi:[1,1,1]" \
      : "+v"(d) : "v"(a), "v"(wpair))

// ---------------- workspace layout (float offsets) ----------------
#define WS_SPEC   0u          // 32*128*1024  [b][t][k]
#define WS_H0     4194304u    // 32*32*128    [b][o][t]
#define WS_ACC    4325376u    // 32*128*32    [b][t][o]
#define WS_V      4456448u    // 32*32*128    [b][c][t]
#define WS_WTIN   4587520u    // 1024*32      [k][o]
#define WS_WST    4620288u    // 32*256       [m][o2]
#define WS_WDT    4628480u    // 256*32       [o2][c]
#define WS_FRAMES 4636672u    // 32*32*2048   [c][f][j]
#define WS_RES    6733824u    // 32*32768     [c][s]
// total 7782400 floats = ~29.7 MB

// ---- 2048-pt complex DIT FFT, input already in bit-reversed order, 256 thr ----
__device__ __forceinline__ void fft2048_stages(float2* buf, int tid) {
  for (int stage = 0; stage < 11; ++stage) {
    int half = 1 << stage;
    float base = -PI_F / (float)half;   // -2*pi/len
    for (int t = tid; t < 1024; t += 256) {
      int j  = t & (half - 1);
      int i0 = ((t >> stage) << (stage + 1)) + j;
      int i1 = i0 + half;
      float s, c;
      __sincosf(base * (float)j, &s, &c);   // e^{-i*2pi/len*j} = c + i*s
      float2 u = buf[i0];
      float2 w = buf[i1];
      float tr = c * w.x - s * w.y;
      float ti = c * w.y + s * w.x;
      buf[i0] = make_float2(u.x + tr, u.y + ti);
      buf[i1] = make_float2(u.x - tr, u.y - ti);
    }
    __syncthreads();
  }
}

// ---------------- fused FFT kernel: STFT pairs + resonance-frame pairs ----------------
// Two real sequences per complex FFT (Hermitian split). blk<2048: STFT pair
// (frames 2f,2f+1 of batch b). blk>=2048: resonance pair (irfft of c^(2g+1),
// c^(2g+2) — real symmetric spectra -> out1=Re(Z), out2=Im(Z)).
__global__ __launch_bounds__(256) void k_fft(const float* __restrict__ audio,
                                             const float* __restrict__ resin,
                                             float* __restrict__ spec,
                                             float* __restrict__ frames) {
  __shared__ float2 buf[2048];
  int blk = blockIdx.x;
  if (blk < 2048) {
    int b  = blk >> 6;
    int f0 = (blk & 63) * 2;      // frames f0, f0+1
    for (int j = threadIdx.x; j < 2048; j += 256) {
      float h = 0.5f - 0.5f * __cosf(0.0030679615757712823f * (float)j); // 2pi/2048
      int i1 = f0 * 256 + j;
      int i2 = i1 + 256;
      float a1 = (i1 < 32768) ? audio[b * 32768 + i1] : 0.f;
      float a2 = (i2 < 32768) ? audio[b * 32768 + i2] : 0.f;
      buf[__brev((unsigned)j) >> 21] = make_float2(a1 * h, a2 * h);
    }
    __syncthreads();
    fft2048_stages(buf, threadIdx.x);
    const float scale = 0.5f * 0.022097086912079608f;  // 0.5 / sqrt(2048)
    for (int k = threadIdx.x; k < 1024; k += 256) {
      float2 zk = buf[k];
      float2 zn = buf[(2048 - k) & 2047];
      float f1r = zk.x + zn.x, f1i = zk.y - zn.y;   // F1 = (Z[k]+conj(Z[N-k]))/2
      float f2r = zk.y + zn.y, f2i = zk.x - zn.x;   // |F2| from (Z[k]-conj(Z[N-k]))/2i
      spec[(b * 128 + f0) * 1024 + k]     = sqrtf(f1r * f1r + f1i * f1i) * scale;
      spec[(b * 128 + f0 + 1) * 1024 + k] = sqrtf(f2r * f2r + f2i * f2i) * scale;
    }
  } else {
    int r = blk - 2048;           // 0..511
    int c = r >> 4;
    int g = r & 15;               // frames 2g (exp 2g+1), 2g+1 (exp 2g+2)
    float e1 = (float)(2 * g + 1);
    for (int k = threadIdx.x; k < 2048; k += 256) {
      int kk = (k <= 1024) ? k : 2048 - k;   // Hermitian (real) extension
      float cv = resin[c * 1025 + kk];
      cv = fminf(fmaxf(cv, 0.f), 0.9999f);
      float m1 = __powf(cv, e1);
      float m2 = m1 * cv;
      buf[__brev((unsigned)k) >> 21] = make_float2(m1, m2);
    }
    __syncthreads();
    fft2048_stages(buf, threadIdx.x);
    for (int j = threadIdx.x; j < 2048; j += 256) {
      float h  = 0.5f - 0.5f * __cosf(0.0030679615757712823f * (float)j);
      float sc = h * (1.f / 2048.f);
      float2 z = buf[j];
      frames[(c * 32 + 2 * g) * 2048 + j]     = z.x * sc;
      frames[(c * 32 + 2 * g + 1) * 2048 + j] = z.y * sc;
    }
  }
}

// ---------------- weight transposes ----------------
__global__ __launch_bounds__(256) void k_prep(const float* __restrict__ Win,
                                              const float* __restrict__ Ws,
                                              const float* __restrict__ Wd,
                                              float* __restrict__ WT,
                                              float* __restrict__ WsT,
                                              float* __restrict__ WdT) {
  int i = blockIdx.x * 256 + threadIdx.x;
  if (i < 32768) { int o = i >> 10, k = i & 1023; WT[k * 32 + o] = Win[i]; }
  if (i < 8192)  { int o2 = i >> 5, m = i & 31;   WsT[m * 256 + o2] = Ws[i]; }
  if (i < 8192)  { int c = i >> 8, o2 = i & 255;  WdT[o2 * 32 + c] = Wd[i]; }
}

// ---------------- proj_in: h0[b,o,t] = sum_k WT[k][o]*spec[b,t,k] + bias ----------------
__global__ __launch_bounds__(256) void k_proj_in(const float* __restrict__ spec,
                                                 const float* __restrict__ WT,
                                                 const float* __restrict__ bias,
                                                 float* __restrict__ h0) {
  __shared__ float specL[8][1024];
  __shared__ float red[32][8][8];   // [o][tt][p]
  int b  = blockIdx.x >> 4;
  int t0 = (blockIdx.x & 15) * 8;
  for (int i = threadIdx.x; i < 8192; i += 256) {
    int tt = i >> 10, k = i & 1023;
    specL[tt][k] = spec[(b * 128 + t0 + tt) * 1024 + k];
  }
  __syncthreads();
  int o = threadIdx.x & 31, p = threadIdx.x >> 5;
  float part[8] = {0.f,0.f,0.f,0.f,0.f,0.f,0.f,0.f};
  for (int i = 0; i < 128; ++i) {
    int k = p * 128 + ((i + p * 4) & 127);   // stagger: conflict-free banks across p
    float w = WT[k * 32 + o];
#pragma unroll
    for (int tt = 0; tt < 8; ++tt) part[tt] += w * specL[tt][k];
  }
#pragma unroll
  for (int tt = 0; tt < 8; ++tt) red[o][tt][p] = part[tt];
  __syncthreads();
  int oo = threadIdx.x >> 3, tt2 = threadIdx.x & 7;
  float s = bias[oo];
#pragma unroll
  for (int p2 = 0; p2 < 8; ++p2) s += red[oo][tt2][p2];
  h0[b * 4096 + oo * 128 + t0 + tt2] = s;
}

// ---------------- 8-block anticausal chain, one WG per batch ----------------
__global__ __launch_bounds__(1024) void k_chain(const float* __restrict__ h0,
                                                const float* __restrict__ bw,
                                                const float* __restrict__ bb,
                                                float* __restrict__ accout) {
  __shared__ float hL[32][128];
  __shared__ float w0L[32][32], w1L[32][32];
  __shared__ float bL[32];
  __shared__ float red[16];
  __shared__ float normL;
  int b = blockIdx.x;
  int tid = threadIdx.x;
  int t = tid & 127, og = tid >> 7;   // og 0..7
  for (int i = tid; i < 4096; i += 1024) hL[i >> 7][i & 127] = h0[b * 4096 + i];
  float acc[4] = {0.f, 0.f, 0.f, 0.f};
  const int DIL[8] = {1, 2, 4, 8, 16, 32, 64, 1};
  for (int blk = 0; blk < 8; ++blk) {
    __syncthreads();
    {
      int o = tid >> 5, m = tid & 31;   // tid < 1024 covers all 32x32
      w0L[o][m] = bw[((blk * 32 + o) * 32 + m) * 2 + 0];
      w1L[o][m] = bw[((blk * 32 + o) * 32 + m) * 2 + 1];
      if (tid < 32) bL[tid] = bb[blk * 32 + tid];
    }
    __syncthreads();
    int d = DIL[blk];
    int t2 = t + d;
    int t2c = (t2 < 128) ? t2 : 0;
    float fm = (t2 < 128) ? 1.f : 0.f;
    float y[4];
#pragma unroll
    for (int n = 0; n < 4; ++n) y[n] = bL[og * 4 + n];
    for (int m = 0; m < 32; ++m) {
      float hv = hL[m][t];
      float hf = hL[m][t2c] * fm;
#pragma unroll
      for (int n = 0; n < 4; ++n)
        y[n] += w0L[og * 4 + n][m] * hv + w1L[og * 4 + n][m] * hf;
    }
    float lmax = 0.f;
#pragma unroll
    for (int n = 0; n < 4; ++n) {
      float s = y[n];
      s = (s > 0.f) ? s : 0.2f * s;     // leaky_relu 0.2
      s += hL[og * 4 + n][t];           // residual
      y[n] = s;
      lmax = fmaxf(lmax, fabsf(s));
    }
    for (int off = 32; off > 0; off >>= 1)
      lmax = fmaxf(lmax, __shfl_down(lmax, off, 64));
    if ((tid & 63) == 0) red[tid >> 6] = lmax;
    __syncthreads();
    if (tid == 0) {
      float m = 0.f;
      for (int i2 = 0; i2 < 16; ++i2) m = fmaxf(m, red[i2]);
      normL = 1.f / (m + 1e-8f);
    }
    __syncthreads();
    float nm = normL;
#pragma unroll
    for (int n = 0; n < 4; ++n) {
      float hv = y[n] * nm;
      hL[og * 4 + n][t] = hv;
      acc[n] += hv;
    }
  }
#pragma unroll
  for (int n = 0; n < 4; ++n)
    accout[b * 4096 + t * 32 + og * 4 + n] = acc[n];
}

// ---------------- sparse (relu proj 32->256, to d_out) + dense (256->32, to ws) ----------------
__global__ __launch_bounds__(256) void k_sparse_dense(const float* __restrict__ acc,
                                                      const float* __restrict__ WsT,
                                                      const float* __restrict__ bs,
                                                      const float* __restrict__ WdT,
                                                      const float* __restrict__ bd,
                                                      float* __restrict__ out_sparse,
                                                      float* __restrict__ v) {
  __shared__ float accL[32];
  __shared__ float sL[256];
  __shared__ float red[8][32];
  int b = blockIdx.x >> 7, t = blockIdx.x & 127;
  int tid = threadIdx.x;
  if (tid < 32) accL[tid] = acc[b * 4096 + t * 32 + tid];
  __syncthreads();
  float s = bs[tid];
  for (int m = 0; m < 32; ++m) s += WsT[m * 256 + tid] * accL[m];
  s = fmaxf(s, 0.f);
  out_sparse[b * 32768 + tid * 128 + t] = s;
  sL[tid] = s;
  __syncthreads();
  int c = tid & 31, p = tid >> 5;
  float part = 0.f;
  for (int j = 0; j < 32; ++j) {
    int o2 = p * 32 + j;
    part += WdT[o2 * 32 + c] * sL[o2];
  }
  red[p][c] = part;
  __syncthreads();
  if (tid < 32) {
    float vv = bd[tid];
    for (int p2 = 0; p2 < 8; ++p2) vv += red[p2][tid];
    v[b * 4096 + tid * 128 + t] = vv;
  }
}

// ---------------- overlap-add (hop 1024): at most 2 frames per sample ----------------
__global__ __launch_bounds__(256) void k_res_assemble(const float* __restrict__ frames,
                                                      float* __restrict__ res) {
  int i = blockIdx.x * 256 + threadIdx.x;   // 0 .. 32*32768
  int c = i >> 15, s = i & 32767;
  int g = s >> 10, j0 = s & 1023;
  float v = frames[(c * 32 + g) * 2048 + j0];
  if (g > 0) v += frames[(c * 32 + g - 1) * 2048 + j0 + 1024];
  res[i] = v;
}

// ---------------- final conv: y[b,256q+r] += sum_c sum_u v[b,c,q-u]*res[c,256u+r] ----------------
// Block = (b, (qt,uc<=qt) pair). Wave w: channels 8w..8w+7; lane owns an r-quad.
// Inner core is explicit v_pk_fma_f32 (inline asm): the w window lives as 16
// v2f pairs straight from ds_read_b128 quads, and VOP3P op_sel broadcasts the
// needed half -> zero splat movs, 2 fp32 FMA/lane/cycle (round-4's C-level
// v4f*scalar was scalarized by the compiler -> 2x VALU, the 62us plateau).
// Cross-wave LDS reduce then one coalesced atomic pass (64 consecutive dwords
// per wave-inst; round-3 showed strided atomics cause 4x HBM writeback).
#define VROW 176   // 31 zeros | 128 v | 17 zeros  (stride 176 floats, 16B-aligned)
__global__ __launch_bounds__(256) void k_conv(const float* __restrict__ v,
                                              const float* __restrict__ res,
                                              float* __restrict__ y) {
  __shared__ __align__(16) float vLp[32 * VROW];   // 22528 B
  __shared__ __align__(16) float yL[4096];         // 16384 B
  int blk = blockIdx.x;            // 1152 = 32 b * 36 pairs
  int b = blk / 36;
  int p = blk - b * 36;
  int qt = (int)((sqrtf(8.f * (float)p + 1.f) - 1.f) * 0.5f + 1e-4f);
  int uc = p - ((qt * (qt + 1)) >> 1);
  int q0 = qt * 16, u0 = uc * 16;
  int wave = threadIdx.x >> 6;
  int lane = threadIdx.x & 63;     // r = 4*lane .. 4*lane+3
  int c0 = wave * 8;

  // zero pads + stage all 32 v rows (shared: all waves same b)
  for (int i = threadIdx.x; i < 32 * VROW; i += 256) vLp[i] = 0.f;
  __syncthreads();
  for (int i = threadIdx.x; i < 4096; i += 256) {
    int c2 = i >> 7, t = i & 127;
    vLp[c2 * VROW + 31 + t] = v[b * 4096 + i];
  }
  __syncthreads();

  v2f accLo[16], accHi[16];
#pragma unroll
  for (int qi = 0; qi < 16; ++qi) { accLo[qi] = (v2f)0.f; accHi[qi] = (v2f)0.f; }

  int wbase = q0 - u0 + 16;        // padded window start, multiple of 16
  const v4f* rres = (const v4f*)res;   // float4 index: c*8192 + u*64 + lane

  for (int c2 = 0; c2 < 8; ++c2) {
    int cc = c0 + c2;
    const v4f* wrow = (const v4f*)&vLp[cc * VROW + wbase];
    v2f wp[16];                    // wp[i] = (w[2i], w[2i+1]); w[m] = v[cc][q0-u0-15+m]
#pragma unroll
    for (int i = 0; i < 8; ++i) {
      v4f t4 = wrow[i];
      wp[2 * i]     = t4.lo;
      wp[2 * i + 1] = t4.hi;
    }
    const v4f* rr = rres + cc * 8192 + u0 * 64 + lane;
    v2f rvLo[8], rvHi[8];
    // u-half 0: u = u0+k -> w index m = 15-k+qi
#pragma unroll
    for (int k = 0; k < 8; ++k) { v4f t = rr[k * 64]; rvLo[k] = t.lo; rvHi[k] = t.hi; }
#pragma unroll
    for (int k = 0; k < 8; ++k)
#pragma unroll
      for (int qi = 0; qi < 16; ++qi) {
        const int m = 15 - k + qi;
        if (m & 1) { PK_FMA_HI(accLo[qi], rvLo[k], wp[m >> 1]);
                     PK_FMA_HI(accHi[qi], rvHi[k], wp[m >> 1]); }
        else       { PK_FMA_LO(accLo[qi], rvLo[k], wp[m >> 1]);
                     PK_FMA_LO(accHi[qi], rvHi[k], wp[m >> 1]); }
      }
    // u-half 1: u = u0+8+k -> m = 7-k+qi
#pragma unroll
    for (int k = 0; k < 8; ++k) { v4f t = rr[(k + 8) * 64]; rvLo[k] = t.lo; rvHi[k] = t.hi; }
#pragma unroll
    for (int k = 0; k < 8; ++k)
#pragma unroll
      for (int qi = 0; qi < 16; ++qi) {
        const int m = 7 - k + qi;
        if (m & 1) { PK_FMA_HI(accLo[qi], rvLo[k], wp[m >> 1]);
                     PK_FMA_HI(accHi[qi], rvHi[k], wp[m >> 1]); }
        else       { PK_FMA_LO(accLo[qi], rvLo[k], wp[m >> 1]);
                     PK_FMA_LO(accHi[qi], rvHi[k], wp[m >> 1]); }
      }
  }

  // cross-wave reduce in LDS: wave 0 stores, waves 1..3 add in turn
  v4f* yv = (v4f*)yL;              // index qi*64 + lane
  for (int w = 0; w < 4; ++w) {
    __syncthreads();
    if (wave == w) {
      if (w == 0) {
#pragma unroll
        for (int qi = 0; qi < 16; ++qi) {
          v4f t; t.lo = accLo[qi]; t.hi = accHi[qi];
          yv[qi * 64 + lane] = t;
        }
      } else {
#pragma unroll
        for (int qi = 0; qi < 16; ++qi) {
          v4f t = yv[qi * 64 + lane];
          t.lo += accLo[qi]; t.hi += accHi[qi];
          yv[qi * 64 + lane] = t;
        }
      }
    }
  }
  __syncthreads();

  // one coalesced atomic pass: 64 consecutive dwords per wave-instruction
  float* yb = y + b * 32768 + q0 * 256;
  for (int i = threadIdx.x; i < 4096; i += 256)
    atomicAdd(yb + i, yL[i]);
}

extern "C" void kernel_launch(void* const* d_in, const int* in_sizes, int n_in,
                              void* d_out, int out_size, void* d_ws, size_t ws_size,
                              hipStream_t stream) {
  const float* audio = (const float*)d_in[0];
  const float* Win   = (const float*)d_in[1];
  const float* bin   = (const float*)d_in[2];
  const float* bw    = (const float*)d_in[3];
  const float* bb    = (const float*)d_in[4];
  const float* Ws    = (const float*)d_in[5];
  const float* bs    = (const float*)d_in[6];
  const float* Wd    = (const float*)d_in[7];
  const float* bd    = (const float*)d_in[8];
  const float* reson = (const float*)d_in[9];

  float* out = (float*)d_out;           // [0,1048576) = y ; [1048576,2097152) = sparse
  float* ws  = (float*)d_ws;

  float* spec   = ws + WS_SPEC;
  float* h0     = ws + WS_H0;
  float* accb   = ws + WS_ACC;
  float* vbuf   = ws + WS_V;
  float* WT     = ws + WS_WTIN;
  float* WsT    = ws + WS_WST;
  float* WdT    = ws + WS_WDT;
  float* frames = ws + WS_FRAMES;
  float* resbuf = ws + WS_RES;

  // zero y region (atomicAdd target); d_out is poisoned before every launch
  hipMemsetAsync(d_out, 0, 1048576u * sizeof(float), stream);

  k_prep<<<128, 256, 0, stream>>>(Win, Ws, Wd, WT, WsT, WdT);
  k_fft<<<2560, 256, 0, stream>>>(audio, reson, spec, frames);
  k_res_assemble<<<4096, 256, 0, stream>>>(frames, resbuf);
  k_proj_in<<<512, 256, 0, stream>>>(spec, WT, bin, h0);
  k_chain<<<32, 1024, 0, stream>>>(h0, bw, bb, accb);
  k_sparse_dense<<<4096, 256, 0, stream>>>(accb, WsT, bs, WdT, bd, out + 1048576, vbuf);
  k_conv<<<1152, 256, 0, stream>>>(vbuf, resbuf, out);
}

// Round 7
// 236.097 us; speedup vs baseline: 1.7252x; 1.0763x over previous
//
#include <hip/hip_runtime.h>

#define PI_F 3.14159265358979323846f

typedef short bf16x8 __attribute__((ext_vector_type(8)));
typedef float f32x4 __attribute__((ext_vector_type(4)));

#define MFMA16(acc, a, b) \
  acc = __builtin_amdgcn_mfma_f32_16x16x32_bf16(a, b, acc, 0, 0, 0)

// ---------------- workspace layout (float offsets) ----------------
#define WS_SPEC   0u          // 32*128*1024  [b][t][k]
#define WS_H0     4194304u    // 32*32*128    [b][o][t]
#define WS_ACC    4325376u    // 32*128*32    [b][t][o]
#define WS_V      4456448u    // 32*32*128    [b][c][t]
#define WS_WTIN   4587520u    // 1024*32      [k][o]
#define WS_WST    4620288u    // 32*256       [m][o2]
#define WS_WDT    4628480u    // 256*32       [o2][c]
#define WS_FRAMES 4636672u    // 32*32*2048   [c][f][j]; after k_res_assemble this
                              // region is DEAD -> reused for Bh/Bl bf16 packs
#define WS_RES    6733824u    // 32*32768     [c][s]
// total 7782400 floats = ~29.7 MB

// ---- 2048-pt complex DIT FFT, input already in bit-reversed order, 256 thr ----
__device__ __forceinline__ void fft2048_stages(float2* buf, int tid) {
  for (int stage = 0; stage < 11; ++stage) {
    int half = 1 << stage;
    float base = -PI_F / (float)half;   // -2*pi/len
    for (int t = tid; t < 1024; t += 256) {
      int j  = t & (half - 1);
      int i0 = ((t >> stage) << (stage + 1)) + j;
      int i1 = i0 + half;
      float s, c;
      __sincosf(base * (float)j, &s, &c);   // e^{-i*2pi/len*j} = c + i*s
      float2 u = buf[i0];
      float2 w = buf[i1];
      float tr = c * w.x - s * w.y;
      float ti = c * w.y + s * w.x;
      buf[i0] = make_float2(u.x + tr, u.y + ti);
      buf[i1] = make_float2(u.x - tr, u.y - ti);
    }
    __syncthreads();
  }
}

// ---------------- fused FFT kernel: STFT pairs + resonance-frame pairs ----------------
__global__ __launch_bounds__(256) void k_fft(const float* __restrict__ audio,
                                             const float* __restrict__ resin,
                                             float* __restrict__ spec,
                                             float* __restrict__ frames) {
  __shared__ float2 buf[2048];
  int blk = blockIdx.x;
  if (blk < 2048) {
    int b  = blk >> 6;
    int f0 = (blk & 63) * 2;      // frames f0, f0+1
    for (int j = threadIdx.x; j < 2048; j += 256) {
      float h = 0.5f - 0.5f * __cosf(0.0030679615757712823f * (float)j); // 2pi/2048
      int i1 = f0 * 256 + j;
      int i2 = i1 + 256;
      float a1 = (i1 < 32768) ? audio[b * 32768 + i1] : 0.f;
      float a2 = (i2 < 32768) ? audio[b * 32768 + i2] : 0.f;
      buf[__brev((unsigned)j) >> 21] = make_float2(a1 * h, a2 * h);
    }
    __syncthreads();
    fft2048_stages(buf, threadIdx.x);
    const float scale = 0.5f * 0.022097086912079608f;  // 0.5 / sqrt(2048)
    for (int k = threadIdx.x; k < 1024; k += 256) {
      float2 zk = buf[k];
      float2 zn = buf[(2048 - k) & 2047];
      float f1r = zk.x + zn.x, f1i = zk.y - zn.y;
      float f2r = zk.y + zn.y, f2i = zk.x - zn.x;
      spec[(b * 128 + f0) * 1024 + k]     = sqrtf(f1r * f1r + f1i * f1i) * scale;
      spec[(b * 128 + f0 + 1) * 1024 + k] = sqrtf(f2r * f2r + f2i * f2i) * scale;
    }
  } else {
    int r = blk - 2048;           // 0..511
    int c = r >> 4;
    int g = r & 15;               // frames 2g (exp 2g+1), 2g+1 (exp 2g+2)
    float e1 = (float)(2 * g + 1);
    for (int k = threadIdx.x; k < 2048; k += 256) {
      int kk = (k <= 1024) ? k : 2048 - k;   // Hermitian (real) extension
      float cv = resin[c * 1025 + kk];
      cv = fminf(fmaxf(cv, 0.f), 0.9999f);
      float m1 = __powf(cv, e1);
      float m2 = m1 * cv;
      buf[__brev((unsigned)k) >> 21] = make_float2(m1, m2);
    }
    __syncthreads();
    fft2048_stages(buf, threadIdx.x);
    for (int j = threadIdx.x; j < 2048; j += 256) {
      float h  = 0.5f - 0.5f * __cosf(0.0030679615757712823f * (float)j);
      float sc = h * (1.f / 2048.f);
      float2 z = buf[j];
      frames[(c * 32 + 2 * g) * 2048 + j]     = z.x * sc;
      frames[(c * 32 + 2 * g + 1) * 2048 + j] = z.y * sc;
    }
  }
}

// ---------------- weight transposes ----------------
__global__ __launch_bounds__(256) void k_prep(const float* __restrict__ Win,
                                              const float* __restrict__ Ws,
                                              const float* __restrict__ Wd,
                                              float* __restrict__ WT,
                                              float* __restrict__ WsT,
                                              float* __restrict__ WdT) {
  int i = blockIdx.x * 256 + threadIdx.x;
  if (i < 32768) { int o = i >> 10, k = i & 1023; WT[k * 32 + o] = Win[i]; }
  if (i < 8192)  { int o2 = i >> 5, m = i & 31;   WsT[m * 256 + o2] = Ws[i]; }
  if (i < 8192)  { int c = i >> 8, o2 = i & 255;  WdT[o2 * 32 + c] = Wd[i]; }
}

// ---------------- proj_in: h0[b,o,t] = sum_k WT[k][o]*spec[b,t,k] + bias ----------------
__global__ __launch_bounds__(256) void k_proj_in(const float* __restrict__ spec,
                                                 const float* __restrict__ WT,
                                                 const float* __restrict__ bias,
                                                 float* __restrict__ h0) {
  __shared__ float specL[8][1024];
  __shared__ float red[32][8][8];   // [o][tt][p]
  int b  = blockIdx.x >> 4;
  int t0 = (blockIdx.x & 15) * 8;
  for (int i = threadIdx.x; i < 8192; i += 256) {
    int tt = i >> 10, k = i & 1023;
    specL[tt][k] = spec[(b * 128 + t0 + tt) * 1024 + k];
  }
  __syncthreads();
  int o = threadIdx.x & 31, p = threadIdx.x >> 5;
  float part[8] = {0.f,0.f,0.f,0.f,0.f,0.f,0.f,0.f};
  for (int i = 0; i < 128; ++i) {
    int k = p * 128 + ((i + p * 4) & 127);   // stagger: conflict-free banks across p
    float w = WT[k * 32 + o];
#pragma unroll
    for (int tt = 0; tt < 8; ++tt) part[tt] += w * specL[tt][k];
  }
#pragma unroll
  for (int tt = 0; tt < 8; ++tt) red[o][tt][p] = part[tt];
  __syncthreads();
  int oo = threadIdx.x >> 3, tt2 = threadIdx.x & 7;
  float s = bias[oo];
#pragma unroll
  for (int p2 = 0; p2 < 8; ++p2) s += red[oo][tt2][p2];
  h0[b * 4096 + oo * 128 + t0 + tt2] = s;
}

// ---------------- 8-block anticausal chain, one WG per batch ----------------
__global__ __launch_bounds__(1024) void k_chain(const float* __restrict__ h0,
                                                const float* __restrict__ bw,
                                                const float* __restrict__ bb,
                                                float* __restrict__ accout) {
  __shared__ float hL[32][128];
  __shared__ float w0L[32][32], w1L[32][32];
  __shared__ float bL[32];
  __shared__ float red[16];
  __shared__ float normL;
  int b = blockIdx.x;
  int tid = threadIdx.x;
  int t = tid & 127, og = tid >> 7;   // og 0..7
  for (int i = tid; i < 4096; i += 1024) hL[i >> 7][i & 127] = h0[b * 4096 + i];
  float acc[4] = {0.f, 0.f, 0.f, 0.f};
  const int DIL[8] = {1, 2, 4, 8, 16, 32, 64, 1};
  for (int blk = 0; blk < 8; ++blk) {
    __syncthreads();
    {
      int o = tid >> 5, m = tid & 31;   // tid < 1024 covers all 32x32
      w0L[o][m] = bw[((blk * 32 + o) * 32 + m) * 2 + 0];
      w1L[o][m] = bw[((blk * 32 + o) * 32 + m) * 2 + 1];
      if (tid < 32) bL[tid] = bb[blk * 32 + tid];
    }
    __syncthreads();
    int d = DIL[blk];
    int t2 = t + d;
    int t2c = (t2 < 128) ? t2 : 0;
    float fm = (t2 < 128) ? 1.f : 0.f;
    float y[4];
#pragma unroll
    for (int n = 0; n < 4; ++n) y[n] = bL[og * 4 + n];
    for (int m = 0; m < 32; ++m) {
      float hv = hL[m][t];
      float hf = hL[m][t2c] * fm;
#pragma unroll
      for (int n = 0; n < 4; ++n)
        y[n] += w0L[og * 4 + n][m] * hv + w1L[og * 4 + n][m] * hf;
    }
    float lmax = 0.f;
#pragma unroll
    for (int n = 0; n < 4; ++n) {
      float s = y[n];
      s = (s > 0.f) ? s : 0.2f * s;     // leaky_relu 0.2
      s += hL[og * 4 + n][t];           // residual
      y[n] = s;
      lmax = fmaxf(lmax, fabsf(s));
    }
    for (int off = 32; off > 0; off >>= 1)
      lmax = fmaxf(lmax, __shfl_down(lmax, off, 64));
    if ((tid & 63) == 0) red[tid >> 6] = lmax;
    __syncthreads();
    if (tid == 0) {
      float m = 0.f;
      for (int i2 = 0; i2 < 16; ++i2) m = fmaxf(m, red[i2]);
      normL = 1.f / (m + 1e-8f);
    }
    __syncthreads();
    float nm = normL;
#pragma unroll
    for (int n = 0; n < 4; ++n) {
      float hv = y[n] * nm;
      hL[og * 4 + n][t] = hv;
      acc[n] += hv;
    }
  }
#pragma unroll
  for (int n = 0; n < 4; ++n)
    accout[b * 4096 + t * 32 + og * 4 + n] = acc[n];
}

// ---------------- sparse (relu proj 32->256, to d_out) + dense (256->32, to ws) ----------------
__global__ __launch_bounds__(256) void k_sparse_dense(const float* __restrict__ acc,
                                                      const float* __restrict__ WsT,
                                                      const float* __restrict__ bs,
                                                      const float* __restrict__ WdT,
                                                      const float* __restrict__ bd,
                                                      float* __restrict__ out_sparse,
                                                      float* __restrict__ v) {
  __shared__ float accL[32];
  __shared__ float sL[256];
  __shared__ float red[8][32];
  int b = blockIdx.x >> 7, t = blockIdx.x & 127;
  int tid = threadIdx.x;
  if (tid < 32) accL[tid] = acc[b * 4096 + t * 32 + tid];
  __syncthreads();
  float s = bs[tid];
  for (int m = 0; m < 32; ++m) s += WsT[m * 256 + tid] * accL[m];
  s = fmaxf(s, 0.f);
  out_sparse[b * 32768 + tid * 128 + t] = s;
  sL[tid] = s;
  __syncthreads();
  int c = tid & 31, p = tid >> 5;
  float part = 0.f;
  for (int j = 0; j < 32; ++j) {
    int o2 = p * 32 + j;
    part += WdT[o2 * 32 + c] * sL[o2];
  }
  red[p][c] = part;
  __syncthreads();
  if (tid < 32) {
    float vv = bd[tid];
    for (int p2 = 0; p2 < 8; ++p2) vv += red[p2][tid];
    v[b * 4096 + tid * 128 + t] = vv;
  }
}

// ---------------- overlap-add (hop 1024): at most 2 frames per sample ----------------
__global__ __launch_bounds__(256) void k_res_assemble(const float* __restrict__ frames,
                                                      float* __restrict__ res) {
  int i = blockIdx.x * 256 + threadIdx.x;   // 0 .. 32*32768
  int c = i >> 15, s = i & 32767;
  int g = s >> 10, j0 = s & 1023;
  float v = frames[(c * 32 + g) * 2048 + j0];
  if (g > 0) v += frames[(c * 32 + g - 1) * 2048 + j0 + 1024];
  res[i] = v;
}

// ---------------- B-pack: res -> bf16 hi/lo in MFMA b-fragment layout ----------------
// Fragment-native layout: unit (bf16x8) index = ((c*16 + o)*16 + nt)*16 + n,
// holding res[c, (8o+j)*256 + nt*16+n] for j=0..7. One 16B store per lane.
__global__ __launch_bounds__(256) void k_bpack(const float* __restrict__ res,
                                               short* __restrict__ Bh,
                                               short* __restrict__ Bl) {
  int c = blockIdx.x >> 4, o = blockIdx.x & 15;
  int r = threadIdx.x;
  bf16x8 hv, lv;
#pragma unroll
  for (int j = 0; j < 8; ++j) {
    float val = res[c * 32768 + (8 * o + j) * 256 + r];
    unsigned bits = __float_as_uint(val);
    float rem = val - __uint_as_float(bits & 0xffff0000u);
    hv[j] = (short)(bits >> 16);
    lv[j] = (short)(__float_as_uint(rem) >> 16);
  }
  int unit = (blockIdx.x * 16 + (r >> 4)) * 16 + (r & 15);
  ((bf16x8*)Bh)[unit] = hv;
  ((bf16x8*)Bl)[unit] = lv;
}

// ---------------- final conv as MFMA GEMM ----------------
// Task (b, qt, uc<=qt): Y[16q x 256r] += A[16 x 512] * B[512 x 256], K=(c,u_loc),
// kk = c*16+u_loc. A[m][kk] = v[b,c,D0+m-(kk&15)] (Toeplitz: only a 31-wide
// window of v!), B from the prepacked fragment layout. fp32 via split-bf16:
// A=Ah+Al, B=Bh+Bl, acc += Ah*Bh + Ah*Bl + Al*Bh (3 MFMA passes, ~2^-16 rel).
// Fragment maps (guide-verified): a: A[m=lane&15][k=quad*8+j]; b: B[n=lane&15]
// [k=quad*8+j]; D: col=lane&15(=r), row=quad*4+reg(=q). Wave w owns n-tiles
// 4w..4w+3 -> no cross-wave reduce. Epilogue atomics: 4 full 64B lines/inst.
// (fp32-VALU version plateaued at 62us = scalar-FMA issue floor; v_pk_fma_f32
// is half-rate per component on CDNA4 -> matrix pipe is the only way past.)
__global__ __launch_bounds__(256) void k_conv(const float* __restrict__ v,
                                              const short* __restrict__ Bh,
                                              const short* __restrict__ Bl,
                                              float* __restrict__ y) {
  __shared__ float vwin[32][33];
  __shared__ __align__(16) short Ah[16 * 520];   // row stride 520 (pad 8) = 2-way banks
  __shared__ __align__(16) short Al[16 * 520];
  int blk = blockIdx.x;            // 1152 = 32 b * 36 pairs
  int b = blk / 36;
  int p = blk - b * 36;
  int qt = (int)((sqrtf(8.f * (float)p + 1.f) - 1.f) * 0.5f + 1e-4f);
  int uc = p - ((qt * (qt + 1)) >> 1);
  int q0 = qt * 16, u0 = uc * 16;
  int D0 = q0 - u0;

  // stage the 31-wide v window (d in [D0-15, D0+15]), zero outside [0,128)
  for (int i = threadIdx.x; i < 1024; i += 256) {
    int c = i >> 5, ii = i & 31;
    int d = D0 - 15 + ii;
    vwin[c][ii] = (d >= 0 && d < 128) ? v[b * 4096 + c * 128 + d] : 0.f;
  }
  __syncthreads();
  // build Toeplitz A, split hi/lo bf16
  for (int idx = threadIdx.x; idx < 8192; idx += 256) {
    int m = idx >> 9, kk = idx & 511;
    float val = vwin[kk >> 4][(m - (kk & 15)) + 15];
    unsigned bits = __float_as_uint(val);
    float rem = val - __uint_as_float(bits & 0xffff0000u);
    Ah[m * 520 + kk] = (short)(bits >> 16);
    Al[m * 520 + kk] = (short)(__float_as_uint(rem) >> 16);
  }
  __syncthreads();

  int lane = threadIdx.x & 63, wave = threadIdx.x >> 6;
  int quad = lane >> 4, l15 = lane & 15;
  int nt0 = wave * 4;

  f32x4 acc[4];
#pragma unroll
  for (int i = 0; i < 4; ++i) acc[i] = (f32x4)0.f;

  const bf16x8* Ah8 = (const bf16x8*)Ah;
  const bf16x8* Al8 = (const bf16x8*)Al;
  const bf16x8* Bh8 = (const bf16x8*)Bh;
  const bf16x8* Bl8 = (const bf16x8*)Bl;
  int aoff = l15 * 65 + quad;        // bf16x8 units; + 4*ks per step
  int og   = 2 * uc + (quad & 1);    // global u-octet for this quad
  int cq   = quad >> 1;              // c = 2*ks + cq

#pragma unroll
  for (int ks = 0; ks < 16; ++ks) {
    bf16x8 avh = Ah8[aoff + 4 * ks];
    bf16x8 avl = Al8[aoff + 4 * ks];
    int c = 2 * ks + cq;
    int bbase = (c * 16 + og) * 256 + l15;   // + nt*16
#pragma unroll
    for (int t = 0; t < 4; ++t) {
      int bi = bbase + (nt0 + t) * 16;
      bf16x8 bvh = Bh8[bi];
      bf16x8 bvl = Bl8[bi];
      MFMA16(acc[t], avh, bvh);
      MFMA16(acc[t], avh, bvl);
      MFMA16(acc[t], avl, bvh);
    }
  }

  float* yb = y + b * 32768 + (q0 + quad * 4) * 256 + l15;
#pragma unroll
  for (int t = 0; t < 4; ++t)
#pragma unroll
    for (int reg = 0; reg < 4; ++reg)
      atomicAdd(yb + reg * 256 + (nt0 + t) * 16, acc[t][reg]);
}

extern "C" void kernel_launch(void* const* d_in, const int* in_sizes, int n_in,
                              void* d_out, int out_size, void* d_ws, size_t ws_size,
                              hipStream_t stream) {
  const float* audio = (const float*)d_in[0];
  const float* Win   = (const float*)d_in[1];
  const float* bin   = (const float*)d_in[2];
  const float* bw    = (const float*)d_in[3];
  const float* bb    = (const float*)d_in[4];
  const float* Ws    = (const float*)d_in[5];
  const float* bs    = (const float*)d_in[6];
  const float* Wd    = (const float*)d_in[7];
  const float* bd    = (const float*)d_in[8];
  const float* reson = (const float*)d_in[9];

  float* out = (float*)d_out;           // [0,1048576) = y ; [1048576,2097152) = sparse
  float* ws  = (float*)d_ws;

  float* spec   = ws + WS_SPEC;
  float* h0     = ws + WS_H0;
  float* accb   = ws + WS_ACC;
  float* vbuf   = ws + WS_V;
  float* WT     = ws + WS_WTIN;
  float* WsT    = ws + WS_WST;
  float* WdT    = ws + WS_WDT;
  float* frames = ws + WS_FRAMES;
  float* resbuf = ws + WS_RES;
  // frames region is dead after k_res_assemble -> reuse for bf16 B packs
  short* Bh = (short*)(ws + WS_FRAMES);            // 1,048,576 bf16 = 2 MB
  short* Bl = (short*)(ws + WS_FRAMES + 524288u);  // 1,048,576 bf16 = 2 MB

  // zero y region (atomicAdd target); d_out is poisoned before every launch
  hipMemsetAsync(d_out, 0, 1048576u * sizeof(float), stream);

  k_prep<<<128, 256, 0, stream>>>(Win, Ws, Wd, WT, WsT, WdT);
  k_fft<<<2560, 256, 0, stream>>>(audio, reson, spec, frames);
  k_res_assemble<<<4096, 256, 0, stream>>>(frames, resbuf);
  k_bpack<<<512, 256, 0, stream>>>(resbuf, Bh, Bl);
  k_proj_in<<<512, 256, 0, stream>>>(spec, WT, bin, h0);
  k_chain<<<32, 1024, 0, stream>>>(h0, bw, bb, accb);
  k_sparse_dense<<<4096, 256, 0, stream>>>(accb, WsT, bs, WdT, bd, out + 1048576, vbuf);
  k_conv<<<1152, 256, 0, stream>>>(vbuf, Bh, Bl, out);
}

// Round 8
// 209.805 us; speedup vs baseline: 1.9414x; 1.1253x over previous
//
#include <hip/hip_runtime.h>

#define PI_F 3.14159265358979323846f

typedef short bf16x8 __attribute__((ext_vector_type(8)));
typedef float f32x4 __attribute__((ext_vector_type(4)));

#define MFMA16(acc, a, b) \
  acc = __builtin_amdgcn_mfma_f32_16x16x32_bf16(a, b, acc, 0, 0, 0)

// ---------------- workspace layout (float offsets) ----------------
#define WS_SPEC   0u          // 32*128*1024  [b][t][k]
#define WS_H0     4194304u    // 32*32*128    [b][o][t]
#define WS_ACC    4325376u    // 32*128*32    [b][t][o]
#define WS_V      4456448u    // 32*32*128    [b][c][t]; ALSO: k_prep stashes the
                              // chain-weight bf16 packs in the first 16384 floats
                              // (region only becomes v after k_sparse_dense,
                              // which runs after k_chain has consumed the packs)
#define WS_WTIN   4587520u    // 1024*32      [k][o]
#define WS_WST    4620288u    // 32*256       [m][o2]
#define WS_WDT    4628480u    // 256*32       [o2][c]
#define WS_FRAMES 4636672u    // 32*32*2048   [c][f][j]; after k_res_assemble this
                              // region is DEAD -> reused for Bh/Bl bf16 packs
#define WS_RES    6733824u    // 32*32768     [c][s]
// total 7782400 floats = ~29.7 MB

// ---- 2048-pt complex DIT FFT, input already in bit-reversed order, 256 thr ----
__device__ __forceinline__ void fft2048_stages(float2* buf, int tid) {
  for (int stage = 0; stage < 11; ++stage) {
    int half = 1 << stage;
    float base = -PI_F / (float)half;   // -2*pi/len
    for (int t = tid; t < 1024; t += 256) {
      int j  = t & (half - 1);
      int i0 = ((t >> stage) << (stage + 1)) + j;
      int i1 = i0 + half;
      float s, c;
      __sincosf(base * (float)j, &s, &c);   // e^{-i*2pi/len*j} = c + i*s
      float2 u = buf[i0];
      float2 w = buf[i1];
      float tr = c * w.x - s * w.y;
      float ti = c * w.y + s * w.x;
      buf[i0] = make_float2(u.x + tr, u.y + ti);
      buf[i1] = make_float2(u.x - tr, u.y - ti);
    }
    __syncthreads();
  }
}

// ---------------- fused FFT kernel: STFT pairs + resonance-frame pairs ----------------
__global__ __launch_bounds__(256) void k_fft(const float* __restrict__ audio,
                                             const float* __restrict__ resin,
                                             float* __restrict__ spec,
                                             float* __restrict__ frames) {
  __shared__ float2 buf[2048];
  int blk = blockIdx.x;
  if (blk < 2048) {
    int b  = blk >> 6;
    int f0 = (blk & 63) * 2;      // frames f0, f0+1
    for (int j = threadIdx.x; j < 2048; j += 256) {
      float h = 0.5f - 0.5f * __cosf(0.0030679615757712823f * (float)j); // 2pi/2048
      int i1 = f0 * 256 + j;
      int i2 = i1 + 256;
      float a1 = (i1 < 32768) ? audio[b * 32768 + i1] : 0.f;
      float a2 = (i2 < 32768) ? audio[b * 32768 + i2] : 0.f;
      buf[__brev((unsigned)j) >> 21] = make_float2(a1 * h, a2 * h);
    }
    __syncthreads();
    fft2048_stages(buf, threadIdx.x);
    const float scale = 0.5f * 0.022097086912079608f;  // 0.5 / sqrt(2048)
    for (int k = threadIdx.x; k < 1024; k += 256) {
      float2 zk = buf[k];
      float2 zn = buf[(2048 - k) & 2047];
      float f1r = zk.x + zn.x, f1i = zk.y - zn.y;
      float f2r = zk.y + zn.y, f2i = zk.x - zn.x;
      spec[(b * 128 + f0) * 1024 + k]     = sqrtf(f1r * f1r + f1i * f1i) * scale;
      spec[(b * 128 + f0 + 1) * 1024 + k] = sqrtf(f2r * f2r + f2i * f2i) * scale;
    }
  } else {
    int r = blk - 2048;           // 0..511
    int c = r >> 4;
    int g = r & 15;               // frames 2g (exp 2g+1), 2g+1 (exp 2g+2)
    float e1 = (float)(2 * g + 1);
    for (int k = threadIdx.x; k < 2048; k += 256) {
      int kk = (k <= 1024) ? k : 2048 - k;   // Hermitian (real) extension
      float cv = resin[c * 1025 + kk];
      cv = fminf(fmaxf(cv, 0.f), 0.9999f);
      float m1 = __powf(cv, e1);
      float m2 = m1 * cv;
      buf[__brev((unsigned)k) >> 21] = make_float2(m1, m2);
    }
    __syncthreads();
    fft2048_stages(buf, threadIdx.x);
    for (int j = threadIdx.x; j < 2048; j += 256) {
      float h  = 0.5f - 0.5f * __cosf(0.0030679615757712823f * (float)j);
      float sc = h * (1.f / 2048.f);
      float2 z = buf[j];
      frames[(c * 32 + 2 * g) * 2048 + j]     = z.x * sc;
      frames[(c * 32 + 2 * g + 1) * 2048 + j] = z.y * sc;
    }
  }
}

// ---------------- weight transposes + chain-weight bf16 hi/lo packs ----------------
// Chain pack layout (B-fragment-native): row = (s*2 + which)*32 + o, 32 bf16/row;
// lane loads b128 at row*32 + quad*8 -> B[n=o][k=quad*8+j] for mfma.
__global__ __launch_bounds__(256) void k_prep(const float* __restrict__ Win,
                                              const float* __restrict__ Ws,
                                              const float* __restrict__ Wd,
                                              const float* __restrict__ bwIn,
                                              float* __restrict__ WT,
                                              float* __restrict__ WsT,
                                              float* __restrict__ WdT,
                                              short* __restrict__ Whg,
                                              short* __restrict__ Wlg) {
  int i = blockIdx.x * 256 + threadIdx.x;
  if (i < 32768) { int o = i >> 10, k = i & 1023; WT[k * 32 + o] = Win[i]; }
  if (i < 8192)  { int o2 = i >> 5, m = i & 31;   WsT[m * 256 + o2] = Ws[i]; }
  if (i < 8192)  { int c = i >> 8, o2 = i & 255;  WdT[o2 * 32 + c] = Wd[i]; }
  if (i < 16384) {
    // i = ((s*32+o)*32+m)*2 + w
    int w = i & 1, m = (i >> 1) & 31, o = (i >> 6) & 31, s = i >> 11;
    float val = bwIn[i];
    unsigned bits = __float_as_uint(val);
    float rem = val - __uint_as_float(bits & 0xffff0000u);
    int row = (s * 2 + w) * 32 + o;
    Whg[row * 32 + m] = (short)(bits >> 16);
    Wlg[row * 32 + m] = (short)(__float_as_uint(rem) >> 16);
  }
}

// ---------------- proj_in: h0[b,o,t] = sum_k WT[k][o]*spec[b,t,k] + bias ----------------
__global__ __launch_bounds__(256) void k_proj_in(const float* __restrict__ spec,
                                                 const float* __restrict__ WT,
                                                 const float* __restrict__ bias,
                                                 float* __restrict__ h0) {
  __shared__ float specL[8][1024];
  __shared__ float red[32][8][8];   // [o][tt][p]
  int b  = blockIdx.x >> 4;
  int t0 = (blockIdx.x & 15) * 8;
  for (int i = threadIdx.x; i < 8192; i += 256) {
    int tt = i >> 10, k = i & 1023;
    specL[tt][k] = spec[(b * 128 + t0 + tt) * 1024 + k];
  }
  __syncthreads();
  int o = threadIdx.x & 31, p = threadIdx.x >> 5;
  float part[8] = {0.f,0.f,0.f,0.f,0.f,0.f,0.f,0.f};
  for (int i = 0; i < 128; ++i) {
    int k = p * 128 + ((i + p * 4) & 127);   // stagger: conflict-free banks across p
    float w = WT[k * 32 + o];
#pragma unroll
    for (int tt = 0; tt < 8; ++tt) part[tt] += w * specL[tt][k];
  }
#pragma unroll
  for (int tt = 0; tt < 8; ++tt) red[o][tt][p] = part[tt];
  __syncthreads();
  int oo = threadIdx.x >> 3, tt2 = threadIdx.x & 7;
  float s = bias[oo];
#pragma unroll
  for (int p2 = 0; p2 < 8; ++p2) s += red[oo][tt2][p2];
  h0[b * 4096 + oo * 128 + t0 + tt2] = s;
}

// ---------------- 8-block anticausal chain as per-step MFMA GEMM pairs ----------------
// One block per batch (serial dependency: per-step global max). Per step:
// Y[128t x 32o] = H^T W0^T + Hshift^T W1^T + bias -> 16 waves x one 16x16 tile,
// 6 MFMA each (bf16 hi/lo split: AhBh + AhBl + AlBh per W). H stored in LDS as
// split-bf16 [t][ch] rows (b128 A-frag reads; rows 128..191 zeroed so the
// anticausal shift t+d reads zeros). Fragment maps identical to k_conv
// (validated): A[m=lane&15][k=quad*8+j], B[n=lane&15][k=quad*8+j],
// D row=quad*4+reg (t), col=lane&15 (o). Max-reduce: wave shuffle -> red[16] ->
// every thread folds 16 values (no serial section). 2 barriers/step (was 4 +
// 64 scalar ds_read_b32/thread/step -> the old 50us was LDS-issue+barrier-bound).
__global__ __launch_bounds__(1024) void k_chain(const float* __restrict__ h0,
                                                const short* __restrict__ Whg,
                                                const short* __restrict__ Wlg,
                                                const float* __restrict__ bb,
                                                float* __restrict__ accout) {
  __shared__ __align__(16) short Hh[192 * 40];   // rows stride 40 bf16 (80 B)
  __shared__ __align__(16) short Hl[192 * 40];
  __shared__ float Hf[128 * 33];                 // fp32 H for exact residual
  __shared__ float bL[256];
  __shared__ float red[16];
  int b = blockIdx.x, tid = threadIdx.x;

  for (int i = tid; i < 4096; i += 1024) {
    int t = i & 127;                 // h0 layout [o][t]
    int o = i >> 7;
    float val = h0[b * 4096 + i];
    Hf[t * 33 + o] = val;
    unsigned bits = __float_as_uint(val);
    float rem = val - __uint_as_float(bits & 0xffff0000u);
    Hh[t * 40 + o] = (short)(bits >> 16);
    Hl[t * 40 + o] = (short)(__float_as_uint(rem) >> 16);
  }
  for (int i = tid; i < 64 * 40; i += 1024) {    // zero pad rows 128..191
    Hh[128 * 40 + i] = 0;
    Hl[128 * 40 + i] = 0;
  }
  if (tid < 256) bL[tid] = bb[tid];
  __syncthreads();

  int wave = tid >> 6, lane = tid & 63;
  int quad = lane >> 4, l15 = lane & 15;
  int t0 = (wave & 7) * 16, o0 = (wave >> 3) * 16;
  int tD = t0 + quad * 4;          // D rows tD..tD+3
  int oD = o0 + l15;               // D col

  const bf16x8* Hh8 = (const bf16x8*)Hh;   // unit = row*5 + quad (40 bf16 = 5 units)
  const bf16x8* Hl8 = (const bf16x8*)Hl;
  const bf16x8* Wh8 = (const bf16x8*)Whg;  // unit = row*4 + quad (32 bf16 = 4 units)
  const bf16x8* Wl8 = (const bf16x8*)Wlg;

  float accsum[4] = {0.f, 0.f, 0.f, 0.f};
  const int DIL[8] = {1, 2, 4, 8, 16, 32, 64, 1};

#pragma unroll
  for (int s = 0; s < 8; ++s) {
    int arow = t0 + l15;
    int frow = arow + DIL[s];        // <= 191, pad rows give zeros
    bf16x8 Ah = Hh8[arow * 5 + quad];
    bf16x8 Al = Hl8[arow * 5 + quad];
    bf16x8 Fh = Hh8[frow * 5 + quad];
    bf16x8 Fl = Hl8[frow * 5 + quad];
    int w0row = ((s * 2 + 0) * 32 + oD) * 4 + quad;
    int w1row = ((s * 2 + 1) * 32 + oD) * 4 + quad;
    bf16x8 B0h = Wh8[w0row], B0l = Wl8[w0row];
    bf16x8 B1h = Wh8[w1row], B1l = Wl8[w1row];
    float bias = bL[s * 32 + oD];
    f32x4 acc = {bias, bias, bias, bias};
    MFMA16(acc, Ah, B0h); MFMA16(acc, Ah, B0l); MFMA16(acc, Al, B0h);
    MFMA16(acc, Fh, B1h); MFMA16(acc, Fh, B1l); MFMA16(acc, Fl, B1h);
    float hnew[4], lmax = 0.f;
#pragma unroll
    for (int r = 0; r < 4; ++r) {
      float sv = acc[r];
      sv = (sv > 0.f) ? sv : 0.2f * sv;       // leaky_relu 0.2
      sv += Hf[(tD + r) * 33 + oD];           // residual (exact fp32)
      hnew[r] = sv;
      lmax = fmaxf(lmax, fabsf(sv));
    }
#pragma unroll
    for (int off = 32; off > 0; off >>= 1)
      lmax = fmaxf(lmax, __shfl_down(lmax, off, 64));
    if (lane == 0) red[wave] = lmax;
    __syncthreads();                 // red visible; all H reads of this step done
    float mx = red[0];
#pragma unroll
    for (int i = 1; i < 16; ++i) mx = fmaxf(mx, red[i]);
    float nm = 1.f / (mx + 1e-8f);
#pragma unroll
    for (int r = 0; r < 4; ++r) {
      float hv = hnew[r] * nm;
      accsum[r] += hv;
      int t = tD + r;
      Hf[t * 33 + oD] = hv;
      unsigned bits = __float_as_uint(hv);
      float rem = hv - __uint_as_float(bits & 0xffff0000u);
      Hh[t * 40 + oD] = (short)(bits >> 16);
      Hl[t * 40 + oD] = (short)(__float_as_uint(rem) >> 16);
    }
    __syncthreads();                 // new H visible for next step
  }
#pragma unroll
  for (int r = 0; r < 4; ++r)
    accout[b * 4096 + (tD + r) * 32 + oD] = accsum[r];
}

// ---------------- sparse (relu proj 32->256, to d_out) + dense (256->32, to ws) ----------------
__global__ __launch_bounds__(256) void k_sparse_dense(const float* __restrict__ acc,
                                                      const float* __restrict__ WsT,
                                                      const float* __restrict__ bs,
                                                      const float* __restrict__ WdT,
                                                      const float* __restrict__ bd,
                                                      float* __restrict__ out_sparse,
                                                      float* __restrict__ v) {
  __shared__ float accL[32];
  __shared__ float sL[256];
  __shared__ float red[8][32];
  int b = blockIdx.x >> 7, t = blockIdx.x & 127;
  int tid = threadIdx.x;
  if (tid < 32) accL[tid] = acc[b * 4096 + t * 32 + tid];
  __syncthreads();
  float s = bs[tid];
  for (int m = 0; m < 32; ++m) s += WsT[m * 256 + tid] * accL[m];
  s = fmaxf(s, 0.f);
  out_sparse[b * 32768 + tid * 128 + t] = s;
  sL[tid] = s;
  __syncthreads();
  int c = tid & 31, p = tid >> 5;
  float part = 0.f;
  for (int j = 0; j < 32; ++j) {
    int o2 = p * 32 + j;
    part += WdT[o2 * 32 + c] * sL[o2];
  }
  red[p][c] = part;
  __syncthreads();
  if (tid < 32) {
    float vv = bd[tid];
    for (int p2 = 0; p2 < 8; ++p2) vv += red[p2][tid];
    v[b * 4096 + tid * 128 + t] = vv;
  }
}

// ---------------- overlap-add (hop 1024): at most 2 frames per sample ----------------
__global__ __launch_bounds__(256) void k_res_assemble(const float* __restrict__ frames,
                                                      float* __restrict__ res) {
  int i = blockIdx.x * 256 + threadIdx.x;   // 0 .. 32*32768
  int c = i >> 15, s = i & 32767;
  int g = s >> 10, j0 = s & 1023;
  float v = frames[(c * 32 + g) * 2048 + j0];
  if (g > 0) v += frames[(c * 32 + g - 1) * 2048 + j0 + 1024];
  res[i] = v;
}

// ---------------- B-pack: res -> bf16 hi/lo in MFMA b-fragment layout ----------------
__global__ __launch_bounds__(256) void k_bpack(const float* __restrict__ res,
                                               short* __restrict__ Bh,
                                               short* __restrict__ Bl) {
  int c = blockIdx.x >> 4, o = blockIdx.x & 15;
  int r = threadIdx.x;
  bf16x8 hv, lv;
#pragma unroll
  for (int j = 0; j < 8; ++j) {
    float val = res[c * 32768 + (8 * o + j) * 256 + r];
    unsigned bits = __float_as_uint(val);
    float rem = val - __uint_as_float(bits & 0xffff0000u);
    hv[j] = (short)(bits >> 16);
    lv[j] = (short)(__float_as_uint(rem) >> 16);
  }
  int unit = (blockIdx.x * 16 + (r >> 4)) * 16 + (r & 15);
  ((bf16x8*)Bh)[unit] = hv;
  ((bf16x8*)Bl)[unit] = lv;
}

// ---------------- final conv as MFMA GEMM ----------------
__global__ __launch_bounds__(256) void k_conv(const float* __restrict__ v,
                                              const short* __restrict__ Bh,
                                              const short* __restrict__ Bl,
                                              float* __restrict__ y) {
  __shared__ float vwin[32][33];
  __shared__ __align__(16) short Ah[16 * 520];   // row stride 520 (pad 8)
  __shared__ __align__(16) short Al[16 * 520];
  int blk = blockIdx.x;            // 1152 = 32 b * 36 pairs
  int b = blk / 36;
  int p = blk - b * 36;
  int qt = (int)((sqrtf(8.f * (float)p + 1.f) - 1.f) * 0.5f + 1e-4f);
  int uc = p - ((qt * (qt + 1)) >> 1);
  int q0 = qt * 16, u0 = uc * 16;
  int D0 = q0 - u0;

  for (int i = threadIdx.x; i < 1024; i += 256) {
    int c = i >> 5, ii = i & 31;
    int d = D0 - 15 + ii;
    vwin[c][ii] = (d >= 0 && d < 128) ? v[b * 4096 + c * 128 + d] : 0.f;
  }
  __syncthreads();
  for (int idx = threadIdx.x; idx < 8192; idx += 256) {
    int m = idx >> 9, kk = idx & 511;
    float val = vwin[kk >> 4][(m - (kk & 15)) + 15];
    unsigned bits = __float_as_uint(val);
    float rem = val - __uint_as_float(bits & 0xffff0000u);
    Ah[m * 520 + kk] = (short)(bits >> 16);
    Al[m * 520 + kk] = (short)(__float_as_uint(rem) >> 16);
  }
  __syncthreads();

  int lane = threadIdx.x & 63, wave = threadIdx.x >> 6;
  int quad = lane >> 4, l15 = lane & 15;
  int nt0 = wave * 4;

  f32x4 acc[4];
#pragma unroll
  for (int i = 0; i < 4; ++i) acc[i] = (f32x4)0.f;

  const bf16x8* Ah8 = (const bf16x8*)Ah;
  const bf16x8* Al8 = (const bf16x8*)Al;
  const bf16x8* Bh8 = (const bf16x8*)Bh;
  const bf16x8* Bl8 = (const bf16x8*)Bl;
  int aoff = l15 * 65 + quad;        // bf16x8 units; + 4*ks per step
  int og   = 2 * uc + (quad & 1);    // global u-octet for this quad
  int cq   = quad >> 1;              // c = 2*ks + cq

#pragma unroll
  for (int ks = 0; ks < 16; ++ks) {
    bf16x8 avh = Ah8[aoff + 4 * ks];
    bf16x8 avl = Al8[aoff + 4 * ks];
    int c = 2 * ks + cq;
    int bbase = (c * 16 + og) * 256 + l15;   // + nt*16
#pragma unroll
    for (int t = 0; t < 4; ++t) {
      int bi = bbase + (nt0 + t) * 16;
      bf16x8 bvh = Bh8[bi];
      bf16x8 bvl = Bl8[bi];
      MFMA16(acc[t], avh, bvh);
      MFMA16(acc[t], avh, bvl);
      MFMA16(acc[t], avl, bvh);
    }
  }

  float* yb = y + b * 32768 + (q0 + quad * 4) * 256 + l15;
#pragma unroll
  for (int t = 0; t < 4; ++t)
#pragma unroll
    for (int reg = 0; reg < 4; ++reg)
      atomicAdd(yb + reg * 256 + (nt0 + t) * 16, acc[t][reg]);
}

extern "C" void kernel_launch(void* const* d_in, const int* in_sizes, int n_in,
                              void* d_out, int out_size, void* d_ws, size_t ws_size,
                              hipStream_t stream) {
  const float* audio = (const float*)d_in[0];
  const float* Win   = (const float*)d_in[1];
  const float* bin   = (const float*)d_in[2];
  const float* bw    = (const float*)d_in[3];
  const float* bb    = (const float*)d_in[4];
  const float* Ws    = (const float*)d_in[5];
  const float* bs    = (const float*)d_in[6];
  const float* Wd    = (const float*)d_in[7];
  const float* bd    = (const float*)d_in[8];
  const float* reson = (const float*)d_in[9];

  float* out = (float*)d_out;           // [0,1048576) = y ; [1048576,2097152) = sparse
  float* ws  = (float*)d_ws;

  float* spec   = ws + WS_SPEC;
  float* h0     = ws + WS_H0;
  float* accb   = ws + WS_ACC;
  float* vbuf   = ws + WS_V;
  float* WT     = ws + WS_WTIN;
  float* WsT    = ws + WS_WST;
  float* WdT    = ws + WS_WDT;
  float* frames = ws + WS_FRAMES;
  float* resbuf = ws + WS_RES;
  // frames region is dead after k_res_assemble -> reuse for bf16 B packs
  short* Bh = (short*)(ws + WS_FRAMES);            // 1,048,576 bf16 = 2 MB
  short* Bl = (short*)(ws + WS_FRAMES + 524288u);  // 1,048,576 bf16 = 2 MB
  // chain-weight packs live in WS_V until k_sparse_dense overwrites it (after k_chain)
  short* Whg = (short*)(ws + WS_V);                // 16384 bf16 = 32 KB
  short* Wlg = (short*)(ws + WS_V + 8192u);        // 16384 bf16 = 32 KB

  // zero y region (atomicAdd target); d_out is poisoned before every launch
  hipMemsetAsync(d_out, 0, 1048576u * sizeof(float), stream);

  k_prep<<<128, 256, 0, stream>>>(Win, Ws, Wd, bw, WT, WsT, WdT, Whg, Wlg);
  k_fft<<<2560, 256, 0, stream>>>(audio, reson, spec, frames);
  k_res_assemble<<<4096, 256, 0, stream>>>(frames, resbuf);
  k_bpack<<<512, 256, 0, stream>>>(resbuf, Bh, Bl);
  k_proj_in<<<512, 256, 0, stream>>>(spec, WT, bin, h0);
  k_chain<<<32, 1024, 0, stream>>>(h0, Whg, Wlg, bb, accb);
  k_sparse_dense<<<4096, 256, 0, stream>>>(accb, WsT, bs, WdT, bd, out + 1048576, vbuf);
  k_conv<<<1152, 256, 0, stream>>>(vbuf, Bh, Bl, out);
}